// Round 19
// baseline (174.939 us; speedup 1.0000x reference)
//
#include <hip/hip_runtime.h>
#include <hip/hip_fp16.h>
#include <math.h>

#define IN_CH 8
#define HID   64
#define EMB   32
#define HBLK  256       // blocks in hist/scatter phases
#define BW    512       // nodes per bucket (dst >> 9)
#define BSH   9         // log2(BW)
#define NBMAX 256       // max buckets supported (N <= 131072)
#define LCAP  18432     // LDS staging capacity in bucket_kernel
#define PSTRIDE (3 * BW + 4)   // worst-case per-bucket padding (mult of 4)
#define P8SCALE 128.0f
#define X8SCALE 16.0f

typedef _Float16 half2n __attribute__((ext_vector_type(2)));
typedef int int4n __attribute__((ext_vector_type(4)));
typedef unsigned uint4n __attribute__((ext_vector_type(4)));

static __device__ __forceinline__ __half2 u2h2(unsigned u) {
    union { unsigned u; __half2 h; } c; c.u = u; return c.h;
}
static __device__ __forceinline__ unsigned h22u(__half2 h) {
    union { unsigned u; __half2 h; } c; c.h = h; return c.u;
}
static __device__ __forceinline__ half2n u2n(unsigned u) {
    union { unsigned u; half2n h; } c; c.u = u; return c.h;
}
static __device__ __forceinline__ half2n mkh2(float a, float b) {
    half2n r; r.x = (_Float16)a; r.y = (_Float16)b; return r;
}
static __device__ __forceinline__ float fdot2w(half2n a, half2n b, float c) {
#if __has_builtin(__builtin_amdgcn_fdot2)
    return __builtin_amdgcn_fdot2(a, b, c, false);
#else
    return (float)a.x * (float)b.x + (float)a.y * (float)b.y + c;
#endif
}

// ------------------------------------------------- fused hist + prep
// blocks [0, HBLK): per-block bucket histogram (ILP-4), commit offsets via atomic.
// blocks [HBLK, ...): x -> biased int8 rows; block HBLK additionally packs weights.
__global__ __launch_bounds__(256) void histprep_kernel(
        const int* __restrict__ ei, int* __restrict__ gcnt, int* __restrict__ blkoff,
        int E, int NB, int per,
        const float* __restrict__ x, unsigned* __restrict__ x8,
        const float* __restrict__ W1l, const float* __restrict__ W1r,
        const float* __restrict__ W2l, const float* __restrict__ W2r,
        unsigned* __restrict__ w1p, unsigned* __restrict__ w2lp,
        unsigned* __restrict__ w2rp, int N) {
    __shared__ int lh[NBMAX];
    int b = blockIdx.x, t = threadIdx.x;
    if (b < HBLK) {
        for (int i = t; i < NB; i += 256) lh[i] = 0;
        __syncthreads();
        int e0 = b * per, e1 = min(e0 + per, E);
        if (e0 < e1) {
            if ((E & 3) == 0) {
                int nv = (e1 - e0) >> 2;
                for (int g = t; g < nv; g += 256) {
                    int4 d = *(const int4*)(ei + E + e0 + g * 4);
                    atomicAdd(&lh[d.x >> BSH], 1);
                    atomicAdd(&lh[d.y >> BSH], 1);
                    atomicAdd(&lh[d.z >> BSH], 1);
                    atomicAdd(&lh[d.w >> BSH], 1);
                }
                for (int e = e0 + nv * 4 + t; e < e1; e += 256)
                    atomicAdd(&lh[ei[E + e] >> BSH], 1);
            } else {
                for (int e = e0 + t; e < e1; e += 256)
                    atomicAdd(&lh[ei[E + e] >> BSH], 1);
            }
        }
        __syncthreads();
        for (int i = t; i < NB; i += 256)
            blkoff[b * NB + i] = atomicAdd(&gcnt[i], lh[i]);
        return;
    }
    // ---- prep branch
    int pb = b - HBLK;
    if (pb == 0) {
        for (int i = t; i < HID * IN_CH; i += 256) {
            int k = i >> 3, c = i & 7;
            w1p[i] = h22u(__floats2half2_rn(W1l[c * HID + k], W1r[c * HID + k]));
        }
        for (int i = t; i < (HID / 2) * EMB; i += 256) {
            int k2 = i >> 5, j = i & 31;
            w2lp[i] = h22u(__floats2half2_rn(W2l[(2 * k2) * EMB + j], W2l[(2 * k2 + 1) * EMB + j]));
            w2rp[i] = h22u(__floats2half2_rn(W2r[(2 * k2) * EMB + j], W2r[(2 * k2 + 1) * EMB + j]));
        }
    }
    int n = pb * 256 + t;
    if (n >= N) return;
    if (n == 0)
        ((uint2*)(x8 + (size_t)N * 2))[0] = make_uint2(0x80808080u, 0x80808080u);
    float4 a = ((const float4*)(x + (size_t)n * IN_CH))[0];
    float4 bb = ((const float4*)(x + (size_t)n * IN_CH))[1];
    float v[8] = {a.x, a.y, a.z, a.w, bb.x, bb.y, bb.z, bb.w};
    unsigned w0 = 0, w1 = 0;
    #pragma unroll
    for (int c = 0; c < 4; c++) {
        int q = min(127, max(-127, __float2int_rn(v[c] * X8SCALE))) + 128;
        w0 |= ((unsigned)q) << (8 * c);
    }
    #pragma unroll
    for (int c = 0; c < 4; c++) {
        int q = min(127, max(-127, __float2int_rn(v[4 + c] * X8SCALE))) + 128;
        w1 |= ((unsigned)q) << (8 * c);
    }
    ((uint2*)(x8 + (size_t)n * 2))[0] = make_uint2(w0, w1);
}

// ------------------------------------------------- bscan: 1 block, exclusive scan of NB counts
__global__ __launch_bounds__(256) void bscan_kernel(const int* __restrict__ gcnt,
                                                    int* __restrict__ sbase, int E, int NB) {
    __shared__ int bsum[256];
    int t = threadIdx.x;
    bsum[t] = (t < NB) ? gcnt[t] : 0;
    __syncthreads();
    for (int off = 1; off < 256; off <<= 1) {
        int v = (t >= off) ? bsum[t - off] : 0;
        __syncthreads();
        bsum[t] += v;
        __syncthreads();
    }
    if (t < NB) sbase[t] = bsum[t] - gcnt[t];
    if (t == 0) sbase[NB] = E;
}

// ------------------------------------------------- scat: scatter edges (packed src|li), ILP-4
__global__ __launch_bounds__(256) void scat_kernel(const int* __restrict__ ei,
                                                   const int* __restrict__ sbase,
                                                   const int* __restrict__ blkoff,
                                                   int* __restrict__ staged, int E, int NB,
                                                   int per) {
    __shared__ int lcur[NBMAX];
    int b = blockIdx.x, t = threadIdx.x;
    for (int i = t; i < NB; i += 256) lcur[i] = sbase[i] + blkoff[b * NB + i];
    __syncthreads();
    int e0 = b * per, e1 = min(e0 + per, E);
    if (e0 >= e1) return;
    if ((E & 3) == 0) {
        int nv = (e1 - e0) >> 2;
        for (int g = t; g < nv; g += 256) {
            int e = e0 + g * 4;
            int4 s4 = *(const int4*)(ei + e);
            int4 d4 = *(const int4*)(ei + E + e);
            int p0 = atomicAdd(&lcur[d4.x >> BSH], 1);
            staged[p0] = s4.x | ((d4.x & (BW - 1)) << 17);
            int p1 = atomicAdd(&lcur[d4.y >> BSH], 1);
            staged[p1] = s4.y | ((d4.y & (BW - 1)) << 17);
            int p2 = atomicAdd(&lcur[d4.z >> BSH], 1);
            staged[p2] = s4.z | ((d4.z & (BW - 1)) << 17);
            int p3 = atomicAdd(&lcur[d4.w >> BSH], 1);
            staged[p3] = s4.w | ((d4.w & (BW - 1)) << 17);
        }
        for (int e = e0 + nv * 4 + t; e < e1; e += 256) {
            int src = ei[e], dst = ei[E + e];
            int pos = atomicAdd(&lcur[dst >> BSH], 1);
            staged[pos] = src | ((dst & (BW - 1)) << 17);
        }
    } else {
        for (int e = e0 + t; e < e1; e += 256) {
            int src = ei[e], dst = ei[E + e];
            int pos = atomicAdd(&lcur[dst >> BSH], 1);
            staged[pos] = src | ((dst & (BW - 1)) << 17);
        }
    }
}

// ------------------------------------------------- bucket: per-bucket CSR build, LDS-staged,
// rows padded to x4 (pad index = N -> zero row), 16B-aligned row starts.
__global__ __launch_bounds__(512) void bucket_kernel(const int* __restrict__ staged,
                                                     const int* __restrict__ sbase,
                                                     int* __restrict__ row_off,
                                                     int* __restrict__ degb,
                                                     int* __restrict__ csr,
                                                     int N, int E, int NB) {
    __shared__ int lst[LCAP];
    __shared__ int cnt[BW], offx[BW], cur[BW];
    int b = blockIdx.x, t = threadIdx.x;
    int base = b * BW;
    int s0 = sbase[b];
    int s1 = sbase[b + 1];
    int len = s1 - s0;
    int cap = min(len, LCAP);
    for (int i = t; i < cap; i += 512) lst[i] = staged[s0 + i];
    cnt[t] = 0;
    __syncthreads();
    for (int i = t; i < cap; i += 512)
        atomicAdd(&cnt[lst[i] >> 17], 1);
    for (int i = cap + t; i < len; i += 512)           // overflow tail (rare)
        atomicAdd(&cnt[staged[s0 + i] >> 17], 1);
    __syncthreads();
    int myc = cnt[t];
    int mypc = (myc + 3) & ~3;                          // padded count
    offx[t] = mypc;
    __syncthreads();
    for (int off = 1; off < BW; off <<= 1) {
        int v = (t >= off) ? offx[t - off] : 0;
        __syncthreads();
        offx[t] += v;
        __syncthreads();
    }
    int pstart = ((s0 + 3) & ~3) + b * PSTRIDE;         // 16B-aligned bucket base
    int pex = offx[t] - mypc;                           // padded exclusive
    int r0abs = pstart + pex;
    if (base + t < N) { row_off[base + t] = r0abs; degb[base + t] = myc; }
    cnt[t] = pex;                                       // reuse as scatter base
    cur[t] = 0;
    __syncthreads();
    for (int i = t; i < cap; i += 512) {
        int v = lst[i];
        int li = v >> 17;
        int pos = pstart + cnt[li] + atomicAdd(&cur[li], 1);
        csr[pos] = v & 0x1FFFF;
    }
    for (int i = cap + t; i < len; i += 512) {          // overflow tail (rare)
        int v = staged[s0 + i];
        int li = v >> 17;
        int pos = pstart + cnt[li] + atomicAdd(&cur[li], 1);
        csr[pos] = v & 0x1FFFF;
    }
    __syncthreads();
    // fill pads with zero-row index N
    for (int p = myc; p < mypc; p++)
        csr[r0abs + p] = N;
}

// ------------------------------------------------- gather1: 2 lanes/node, NT int4 bulk indices
__global__ __launch_bounds__(256) void gather1_kernel(
        const unsigned* __restrict__ x8, const int* __restrict__ row_off,
        const int* __restrict__ degb, const int* __restrict__ csr,
        float* __restrict__ aggr, int N) {
    int t = threadIdx.x;
    int l = t >> 1, q = t & 1;
    int node = blockIdx.x * 128 + l;
    if (node >= N) return;
    int r0 = row_off[node];
    int dg = degb[node];
    int nv = (dg + 3) >> 2;
    const unsigned M = 0x00FF00FFu;
    unsigned Al = 0, Ah = 0;
    for (int i = 0; i < nv; i++) {
        int4n id4 = __builtin_nontemporal_load((const int4n*)(csr + r0 + i * 4));
        unsigned u0 = x8[(size_t)id4.x * 2 + q];
        unsigned u1 = x8[(size_t)id4.y * 2 + q];
        unsigned u2 = x8[(size_t)id4.z * 2 + q];
        unsigned u3 = x8[(size_t)id4.w * 2 + q];
        Al += u0 & M; Ah += (u0 >> 8) & M;
        Al += u1 & M; Ah += (u1 >> 8) & M;
        Al += u2 & M; Ah += (u2 >> 8) & M;
        Al += u3 & M; Ah += (u3 >> 8) & M;
    }
    float bias = 128.0f * (float)(4 * nv);              // pads are biased zeros
    float inv = 1.0f / (X8SCALE * fmaxf((float)dg, 1.0f));
    float4 o;
    o.x = ((float)(Al & 0xFFFF) - bias) * inv;
    o.y = ((float)(Ah & 0xFFFF) - bias) * inv;
    o.z = ((float)(Al >> 16) - bias) * inv;
    o.w = ((float)(Ah >> 16) - bias) * inv;
    ((float4*)(aggr + (size_t)node * IN_CH))[q] = o;
}

// ------------------------------------------------- dense1b: wave-uniform j-quarter split
__global__ __launch_bounds__(256) void dense1b_kernel(
        const float* __restrict__ x, const float* __restrict__ aggr,
        const float* __restrict__ b1, const float* __restrict__ b2,
        const unsigned* __restrict__ w1p, const unsigned* __restrict__ w2lp,
        const unsigned* __restrict__ w2rp,
        unsigned* __restrict__ p8, unsigned* __restrict__ selfh, int N) {
    int t = threadIdx.x;
    int w = t >> 6;                   // j-quarter 0..3 (wave-uniform)
    int lane = t & 63;
    int n = blockIdx.x * 64 + lane;
    if (n >= N) return;
    if (n == 0 && w == 0) {
        uint4 z = make_uint4(0x80808080u, 0x80808080u, 0x80808080u, 0x80808080u);
        ((uint4*)(p8 + (size_t)N * 8))[0] = z;
        ((uint4*)(p8 + (size_t)N * 8))[1] = z;
    }

    half2n uv[IN_CH];
    {
        float4 a0 = ((const float4*)(aggr + (size_t)n * IN_CH))[0];
        float4 a1 = ((const float4*)(aggr + (size_t)n * IN_CH))[1];
        float4 b0 = ((const float4*)(x + (size_t)n * IN_CH))[0];
        float4 b1v = ((const float4*)(x + (size_t)n * IN_CH))[1];
        uv[0] = mkh2(a0.x, b0.x); uv[1] = mkh2(a0.y, b0.y);
        uv[2] = mkh2(a0.z, b0.z); uv[3] = mkh2(a0.w, b0.w);
        uv[4] = mkh2(a1.x, b1v.x); uv[5] = mkh2(a1.y, b1v.y);
        uv[6] = mkh2(a1.z, b1v.z); uv[7] = mkh2(a1.w, b1v.w);
    }

    float pacc[8], sacc[8];
    const unsigned* w2lq = w2lp + w * 8;   // quarter base (wave-uniform)
    const unsigned* w2rq = w2rp + w * 8;
    #pragma unroll
    for (int j = 0; j < 8; j++) { pacc[j] = 0.0f; sacc[j] = b2[w * 8 + j]; }

    #pragma unroll 2
    for (int k2 = 0; k2 < HID / 2; k2++) {
        int k = 2 * k2;
        float h0 = b1[k], h1 = b1[k + 1];
        #pragma unroll
        for (int c = 0; c < IN_CH; c++) {
            h0 = fdot2w(uv[c], u2n(w1p[k * 8 + c]), h0);
            h1 = fdot2w(uv[c], u2n(w1p[(k + 1) * 8 + c]), h1);
        }
        h0 = fmaxf(h0, 0.0f);
        h1 = fmaxf(h1, 0.0f);
        half2n hh = mkh2(h0, h1);
        #pragma unroll
        for (int j = 0; j < 8; j++) {
            pacc[j] = fdot2w(hh, u2n(w2lq[k2 * EMB + j]), pacc[j]);
            sacc[j] = fdot2w(hh, u2n(w2rq[k2 * EMB + j]), sacc[j]);
        }
    }

    unsigned up[2];
    #pragma unroll
    for (int m = 0; m < 2; m++) {
        int q0 = min(127, max(-127, __float2int_rn(pacc[4 * m + 0] * P8SCALE)));
        int q1 = min(127, max(-127, __float2int_rn(pacc[4 * m + 1] * P8SCALE)));
        int q2 = min(127, max(-127, __float2int_rn(pacc[4 * m + 2] * P8SCALE)));
        int q3 = min(127, max(-127, __float2int_rn(pacc[4 * m + 3] * P8SCALE)));
        up[m] = ((unsigned)(q0 & 255) | ((unsigned)(q1 & 255) << 8)
              | ((unsigned)(q2 & 255) << 16) | ((unsigned)(q3 & 255) << 24)) ^ 0x80808080u;
    }
    ((uint2*)(p8 + (size_t)n * 8 + w * 2))[0] = make_uint2(up[0], up[1]);

    unsigned us[4];
    #pragma unroll
    for (int m = 0; m < 4; m++)
        us[m] = h22u(__floats2half2_rn(sacc[2 * m], sacc[2 * m + 1]));
    ((uint4*)(selfh + (size_t)n * 16 + w * 4))[0] = make_uint4(us[0], us[1], us[2], us[3]);
}

// ------------------------------------------------- gather2: 2 lanes/node, NT int4 indices,
// NT selfh; p8 stays L2-resident. Phase 2: thread-per-node head MLP.
__global__ __launch_bounds__(128) void gather2_kernel(
        const unsigned* __restrict__ p8, const unsigned* __restrict__ selfh,
        const int* __restrict__ row_off, const int* __restrict__ degb,
        const int* __restrict__ csr,
        const float* __restrict__ Wh1, const float* __restrict__ bh1,
        const float* __restrict__ Wh2, const float* __restrict__ bh2,
        float* __restrict__ out, int N) {
    __shared__ float zs[64 * 33];
    __shared__ float sW1[EMB * 16];
    __shared__ float sbh1[16];
    __shared__ float sW2[16];
    __shared__ float sbh2;
    int t = threadIdx.x;
    for (int i = t; i < EMB * 16; i += 128) sW1[i] = Wh1[i];
    if (t < 16) { sbh1[t] = bh1[t]; sW2[t] = Wh2[t]; }
    if (t == 0) sbh2 = bh2[0];

    int l = t >> 1, q = t & 1;
    int node = blockIdx.x * 64 + l;

    if (node < N) {
        int r0 = row_off[node];
        int dg = degb[node];
        int nv = (dg + 3) >> 2;
        const unsigned M = 0x00FF00FFu;
        unsigned A[8];
        #pragma unroll
        for (int j = 0; j < 8; j++) A[j] = 0;

        for (int i = 0; i < nv; i++) {
            int4n id4 = __builtin_nontemporal_load((const int4n*)(csr + r0 + i * 4));
            uint4 u0 = *(const uint4*)(p8 + (size_t)id4.x * 8 + q * 4);
            uint4 u1 = *(const uint4*)(p8 + (size_t)id4.y * 8 + q * 4);
            uint4 u2 = *(const uint4*)(p8 + (size_t)id4.z * 8 + q * 4);
            uint4 u3 = *(const uint4*)(p8 + (size_t)id4.w * 8 + q * 4);
            A[0] += u0.x & M; A[1] += (u0.x >> 8) & M;
            A[2] += u0.y & M; A[3] += (u0.y >> 8) & M;
            A[4] += u0.z & M; A[5] += (u0.z >> 8) & M;
            A[6] += u0.w & M; A[7] += (u0.w >> 8) & M;
            A[0] += u1.x & M; A[1] += (u1.x >> 8) & M;
            A[2] += u1.y & M; A[3] += (u1.y >> 8) & M;
            A[4] += u1.z & M; A[5] += (u1.z >> 8) & M;
            A[6] += u1.w & M; A[7] += (u1.w >> 8) & M;
            A[0] += u2.x & M; A[1] += (u2.x >> 8) & M;
            A[2] += u2.y & M; A[3] += (u2.y >> 8) & M;
            A[4] += u2.z & M; A[5] += (u2.z >> 8) & M;
            A[6] += u2.w & M; A[7] += (u2.w >> 8) & M;
            A[0] += u3.x & M; A[1] += (u3.x >> 8) & M;
            A[2] += u3.y & M; A[3] += (u3.y >> 8) & M;
            A[4] += u3.z & M; A[5] += (u3.z >> 8) & M;
            A[6] += u3.w & M; A[7] += (u3.w >> 8) & M;
        }

        float bias = 128.0f * (float)(4 * nv);          // pads are biased zeros
        float sc = (1.0f / P8SCALE) / fmaxf((float)dg, 1.0f);
        uint4n s0 = __builtin_nontemporal_load((const uint4n*)(selfh + (size_t)node * 16 + q * 8));
        uint4n s1 = __builtin_nontemporal_load((const uint4n*)(selfh + (size_t)node * 16 + q * 8 + 4));
        float sf[16];
        { float2 c = __half22float2(u2h2(s0.x)); sf[0] = c.x; sf[1] = c.y; }
        { float2 c = __half22float2(u2h2(s0.y)); sf[2] = c.x; sf[3] = c.y; }
        { float2 c = __half22float2(u2h2(s0.z)); sf[4] = c.x; sf[5] = c.y; }
        { float2 c = __half22float2(u2h2(s0.w)); sf[6] = c.x; sf[7] = c.y; }
        { float2 c = __half22float2(u2h2(s1.x)); sf[8] = c.x; sf[9] = c.y; }
        { float2 c = __half22float2(u2h2(s1.y)); sf[10] = c.x; sf[11] = c.y; }
        { float2 c = __half22float2(u2h2(s1.z)); sf[12] = c.x; sf[13] = c.y; }
        { float2 c = __half22float2(u2h2(s1.w)); sf[14] = c.x; sf[15] = c.y; }

        float* zrow = zs + l * 33 + q * 16;
        #pragma unroll
        for (int w = 0; w < 4; w++) {
            float c0 = ((float)(A[2 * w] & 0xFFFF) - bias) * sc;
            float c1 = ((float)(A[2 * w + 1] & 0xFFFF) - bias) * sc;
            float c2 = ((float)(A[2 * w] >> 16) - bias) * sc;
            float c3 = ((float)(A[2 * w + 1] >> 16) - bias) * sc;
            zrow[4 * w + 0] = fmaxf(c0 + sf[4 * w + 0], 0.0f);
            zrow[4 * w + 1] = fmaxf(c1 + sf[4 * w + 1], 0.0f);
            zrow[4 * w + 2] = fmaxf(c2 + sf[4 * w + 2], 0.0f);
            zrow[4 * w + 3] = fmaxf(c3 + sf[4 * w + 3], 0.0f);
        }
    }
    __syncthreads();

    if (t < 64) {
        int node2 = blockIdx.x * 64 + t;
        if (node2 < N) {
            float zr[EMB];
            #pragma unroll
            for (int k = 0; k < EMB; k++) zr[k] = zs[t * 33 + k];
            float logit = sbh2;
            #pragma unroll
            for (int i = 0; i < 16; i++) {
                float acc = sbh1[i];
                #pragma unroll
                for (int k = 0; k < EMB; k++) acc += zr[k] * sW1[k * 16 + i];
                logit += fmaxf(acc, 0.0f) * sW2[i];
            }
            out[node2] = 1.0f / (1.0f + expf(-logit));
        }
    }
}

// ---------------------------------------------------------------- launch
extern "C" void kernel_launch(void* const* d_in, const int* in_sizes, int n_in,
                              void* d_out, int out_size, void* d_ws, size_t ws_size,
                              hipStream_t stream) {
    const float* x   = (const float*)d_in[0];
    const int*   ei  = (const int*)d_in[1];
    const float* W1l = (const float*)d_in[2];
    const float* b1  = (const float*)d_in[3];
    const float* W1r = (const float*)d_in[4];
    const float* W2l = (const float*)d_in[5];
    const float* b2  = (const float*)d_in[6];
    const float* W2r = (const float*)d_in[7];
    const float* Wh1 = (const float*)d_in[8];
    const float* bh1 = (const float*)d_in[9];
    const float* Wh2 = (const float*)d_in[10];
    const float* bh2 = (const float*)d_in[11];

    int N = in_sizes[0] / IN_CH;     // 100000
    int E = in_sizes[1] / 2;         // 3200000
    int NB = (N + BW - 1) / BW;      // 196 buckets
    int M  = NB * HBLK;              // blkoff cells
    int per = (((E + HBLK - 1) / HBLK) + 3) & ~3;   // per-block edge span, x4 aligned
    int CSRSZ = E + (NB + 1) * PSTRIDE;             // padded CSR capacity
    int PB = (N + 255) / 256;                       // prep blocks

    // workspace layout (all segments x4-int aligned):
    // [staged E][blkoff M][gcnt NB4][sbase NB4+4][row_off N4][degb N4][csr CSRSZ]
    // [x8 2(N+2)][aggr 8N f32][selfh 16N][p8 8(N+1)+pad][w1p 512][w2lp 1024][w2rp 1024]
    int N4 = (N + 3) & ~3;
    int NB4 = (NB + 3) & ~3;
    int* staged   = (int*)d_ws;
    int* blkoff   = staged + E;                     // E mult of 4
    int* gcnt     = blkoff + M;                     // M mult of 4
    int* sbase    = gcnt + NB4;
    int* row_off  = sbase + NB4 + 4;
    int* degb     = row_off + N4;
    int* csr      = degb + N4;
    unsigned* x8  = (unsigned*)(csr + CSRSZ);       // CSRSZ mult of 4
    float* aggr   = (float*)(x8 + (size_t)(N + 2) * 2);
    unsigned* selfh = (unsigned*)(aggr + (size_t)N * IN_CH);
    unsigned* p8  = selfh + (size_t)N * 16;
    unsigned* w1p = p8 + (size_t)(N + 1) * 8 + 4;   // keep x4 alignment
    unsigned* w2lp = w1p + HID * IN_CH;
    unsigned* w2rp = w2lp + (HID / 2) * EMB;

    (void)hipMemsetAsync(gcnt, 0, sizeof(int) * NB4, stream);
    histprep_kernel<<<HBLK + PB, 256, 0, stream>>>(ei, gcnt, blkoff, E, NB, per,
                                                   x, x8, W1l, W1r, W2l, W2r,
                                                   w1p, w2lp, w2rp, N);
    bscan_kernel  <<<1, 256, 0, stream>>>(gcnt, sbase, E, NB);
    scat_kernel   <<<HBLK, 256, 0, stream>>>(ei, sbase, blkoff, staged, E, NB, per);
    bucket_kernel <<<NB, 512, 0, stream>>>(staged, sbase, row_off, degb, csr, N, E, NB);
    gather1_kernel<<<(N + 127) / 128, 256, 0, stream>>>(x8, row_off, degb, csr, aggr, N);
    dense1b_kernel<<<(N + 63) / 64, 256, 0, stream>>>(x, aggr, b1, b2,
                                                      w1p, w2lp, w2rp, p8, selfh, N);
    gather2_kernel<<<(N + 63) / 64, 128, 0, stream>>>(p8, selfh, row_off, degb, csr,
                                                      Wh1, bh1, Wh2, bh2, (float*)d_out, N);
}

// Round 20
// 153.963 us; speedup vs baseline: 1.1362x; 1.1362x over previous
//
#include <hip/hip_runtime.h>
#include <hip/hip_fp16.h>
#include <math.h>

#define IN_CH 8
#define HID   64
#define EMB   32
#define HBLK  256       // blocks in hist/scatter phases
#define BW    512       // nodes per bucket (dst >> 9)
#define BSH   9         // log2(BW)
#define NBMAX 256       // max buckets supported (N <= 131072)
#define LCAP  18432     // LDS staging capacity in bucket_kernel
#define PSTRIDE (3 * BW + 4)   // worst-case per-bucket padding (mult of 4)
#define P8SCALE 128.0f
#define X8SCALE 16.0f

typedef _Float16 half2n __attribute__((ext_vector_type(2)));

static __device__ __forceinline__ __half2 u2h2(unsigned u) {
    union { unsigned u; __half2 h; } c; c.u = u; return c.h;
}
static __device__ __forceinline__ unsigned h22u(__half2 h) {
    union { unsigned u; __half2 h; } c; c.h = h; return c.u;
}
static __device__ __forceinline__ half2n u2n(unsigned u) {
    union { unsigned u; half2n h; } c; c.u = u; return c.h;
}
static __device__ __forceinline__ half2n mkh2(float a, float b) {
    half2n r; r.x = (_Float16)a; r.y = (_Float16)b; return r;
}
static __device__ __forceinline__ float fdot2w(half2n a, half2n b, float c) {
#if __has_builtin(__builtin_amdgcn_fdot2)
    return __builtin_amdgcn_fdot2(a, b, c, false);
#else
    return (float)a.x * (float)b.x + (float)a.y * (float)b.y + c;
#endif
}

// ------------------------------------------------- fused hist + prep
// blocks [0, HBLK): per-block bucket histogram (ILP-4), commit offsets via atomic.
// blocks [HBLK, ...): x -> biased int8 rows; block HBLK additionally packs weights.
__global__ __launch_bounds__(256) void histprep_kernel(
        const int* __restrict__ ei, int* __restrict__ gcnt, int* __restrict__ blkoff,
        int E, int NB, int per,
        const float* __restrict__ x, unsigned* __restrict__ x8,
        const float* __restrict__ W1l, const float* __restrict__ W1r,
        const float* __restrict__ W2l, const float* __restrict__ W2r,
        unsigned* __restrict__ w1p, unsigned* __restrict__ w2lp,
        unsigned* __restrict__ w2rp, int N) {
    __shared__ int lh[NBMAX];
    int b = blockIdx.x, t = threadIdx.x;
    if (b < HBLK) {
        for (int i = t; i < NB; i += 256) lh[i] = 0;
        __syncthreads();
        int e0 = b * per, e1 = min(e0 + per, E);
        if (e0 < e1) {
            if ((E & 3) == 0) {
                int nv = (e1 - e0) >> 2;
                for (int g = t; g < nv; g += 256) {
                    int4 d = *(const int4*)(ei + E + e0 + g * 4);
                    atomicAdd(&lh[d.x >> BSH], 1);
                    atomicAdd(&lh[d.y >> BSH], 1);
                    atomicAdd(&lh[d.z >> BSH], 1);
                    atomicAdd(&lh[d.w >> BSH], 1);
                }
                for (int e = e0 + nv * 4 + t; e < e1; e += 256)
                    atomicAdd(&lh[ei[E + e] >> BSH], 1);
            } else {
                for (int e = e0 + t; e < e1; e += 256)
                    atomicAdd(&lh[ei[E + e] >> BSH], 1);
            }
        }
        __syncthreads();
        for (int i = t; i < NB; i += 256)
            blkoff[b * NB + i] = atomicAdd(&gcnt[i], lh[i]);
        return;
    }
    // ---- prep branch
    int pb = b - HBLK;
    if (pb == 0) {
        for (int i = t; i < HID * IN_CH; i += 256) {
            int k = i >> 3, c = i & 7;
            w1p[i] = h22u(__floats2half2_rn(W1l[c * HID + k], W1r[c * HID + k]));
        }
        for (int i = t; i < (HID / 2) * EMB; i += 256) {
            int k2 = i >> 5, j = i & 31;
            w2lp[i] = h22u(__floats2half2_rn(W2l[(2 * k2) * EMB + j], W2l[(2 * k2 + 1) * EMB + j]));
            w2rp[i] = h22u(__floats2half2_rn(W2r[(2 * k2) * EMB + j], W2r[(2 * k2 + 1) * EMB + j]));
        }
    }
    int n = pb * 256 + t;
    if (n >= N) return;
    if (n == 0)
        ((uint2*)(x8 + (size_t)N * 2))[0] = make_uint2(0x80808080u, 0x80808080u);
    float4 a = ((const float4*)(x + (size_t)n * IN_CH))[0];
    float4 bb = ((const float4*)(x + (size_t)n * IN_CH))[1];
    float v[8] = {a.x, a.y, a.z, a.w, bb.x, bb.y, bb.z, bb.w};
    unsigned w0 = 0, w1 = 0;
    #pragma unroll
    for (int c = 0; c < 4; c++) {
        int q = min(127, max(-127, __float2int_rn(v[c] * X8SCALE))) + 128;
        w0 |= ((unsigned)q) << (8 * c);
    }
    #pragma unroll
    for (int c = 0; c < 4; c++) {
        int q = min(127, max(-127, __float2int_rn(v[4 + c] * X8SCALE))) + 128;
        w1 |= ((unsigned)q) << (8 * c);
    }
    ((uint2*)(x8 + (size_t)n * 2))[0] = make_uint2(w0, w1);
}

// ------------------------------------------------- bscan: 1 block, exclusive scan of NB counts
__global__ __launch_bounds__(256) void bscan_kernel(const int* __restrict__ gcnt,
                                                    int* __restrict__ sbase, int E, int NB) {
    __shared__ int bsum[256];
    int t = threadIdx.x;
    bsum[t] = (t < NB) ? gcnt[t] : 0;
    __syncthreads();
    for (int off = 1; off < 256; off <<= 1) {
        int v = (t >= off) ? bsum[t - off] : 0;
        __syncthreads();
        bsum[t] += v;
        __syncthreads();
    }
    if (t < NB) sbase[t] = bsum[t] - gcnt[t];
    if (t == 0) sbase[NB] = E;
}

// ------------------------------------------------- scat: scatter edges (packed src|li), ILP-4
__global__ __launch_bounds__(256) void scat_kernel(const int* __restrict__ ei,
                                                   const int* __restrict__ sbase,
                                                   const int* __restrict__ blkoff,
                                                   int* __restrict__ staged, int E, int NB,
                                                   int per) {
    __shared__ int lcur[NBMAX];
    int b = blockIdx.x, t = threadIdx.x;
    for (int i = t; i < NB; i += 256) lcur[i] = sbase[i] + blkoff[b * NB + i];
    __syncthreads();
    int e0 = b * per, e1 = min(e0 + per, E);
    if (e0 >= e1) return;
    if ((E & 3) == 0) {
        int nv = (e1 - e0) >> 2;
        for (int g = t; g < nv; g += 256) {
            int e = e0 + g * 4;
            int4 s4 = *(const int4*)(ei + e);
            int4 d4 = *(const int4*)(ei + E + e);
            int p0 = atomicAdd(&lcur[d4.x >> BSH], 1);
            staged[p0] = s4.x | ((d4.x & (BW - 1)) << 17);
            int p1 = atomicAdd(&lcur[d4.y >> BSH], 1);
            staged[p1] = s4.y | ((d4.y & (BW - 1)) << 17);
            int p2 = atomicAdd(&lcur[d4.z >> BSH], 1);
            staged[p2] = s4.z | ((d4.z & (BW - 1)) << 17);
            int p3 = atomicAdd(&lcur[d4.w >> BSH], 1);
            staged[p3] = s4.w | ((d4.w & (BW - 1)) << 17);
        }
        for (int e = e0 + nv * 4 + t; e < e1; e += 256) {
            int src = ei[e], dst = ei[E + e];
            int pos = atomicAdd(&lcur[dst >> BSH], 1);
            staged[pos] = src | ((dst & (BW - 1)) << 17);
        }
    } else {
        for (int e = e0 + t; e < e1; e += 256) {
            int src = ei[e], dst = ei[E + e];
            int pos = atomicAdd(&lcur[dst >> BSH], 1);
            staged[pos] = src | ((dst & (BW - 1)) << 17);
        }
    }
}

// ------------------------------------------------- bucket: per-bucket CSR build, LDS-staged,
// rows padded to x4 (pad index = N -> zero row), 16B-aligned row starts.
__global__ __launch_bounds__(512) void bucket_kernel(const int* __restrict__ staged,
                                                     const int* __restrict__ sbase,
                                                     int* __restrict__ row_off,
                                                     int* __restrict__ degb,
                                                     int* __restrict__ csr,
                                                     int N, int E, int NB) {
    __shared__ int lst[LCAP];
    __shared__ int cnt[BW], offx[BW], cur[BW];
    int b = blockIdx.x, t = threadIdx.x;
    int base = b * BW;
    int s0 = sbase[b];
    int s1 = sbase[b + 1];
    int len = s1 - s0;
    int cap = min(len, LCAP);
    for (int i = t; i < cap; i += 512) lst[i] = staged[s0 + i];
    cnt[t] = 0;
    __syncthreads();
    for (int i = t; i < cap; i += 512)
        atomicAdd(&cnt[lst[i] >> 17], 1);
    for (int i = cap + t; i < len; i += 512)           // overflow tail (rare)
        atomicAdd(&cnt[staged[s0 + i] >> 17], 1);
    __syncthreads();
    int myc = cnt[t];
    int mypc = (myc + 3) & ~3;                          // padded count
    offx[t] = mypc;
    __syncthreads();
    for (int off = 1; off < BW; off <<= 1) {
        int v = (t >= off) ? offx[t - off] : 0;
        __syncthreads();
        offx[t] += v;
        __syncthreads();
    }
    int pstart = ((s0 + 3) & ~3) + b * PSTRIDE;         // 16B-aligned bucket base
    int pex = offx[t] - mypc;                           // padded exclusive
    int r0abs = pstart + pex;
    if (base + t < N) { row_off[base + t] = r0abs; degb[base + t] = myc; }
    cnt[t] = pex;                                       // reuse as scatter base
    cur[t] = 0;
    __syncthreads();
    for (int i = t; i < cap; i += 512) {
        int v = lst[i];
        int li = v >> 17;
        int pos = pstart + cnt[li] + atomicAdd(&cur[li], 1);
        csr[pos] = v & 0x1FFFF;
    }
    for (int i = cap + t; i < len; i += 512) {          // overflow tail (rare)
        int v = staged[s0 + i];
        int li = v >> 17;
        int pos = pstart + cnt[li] + atomicAdd(&cur[li], 1);
        csr[pos] = v & 0x1FFFF;
    }
    __syncthreads();
    // fill pads with zero-row index N
    for (int p = myc; p < mypc; p++)
        csr[r0abs + p] = N;
}

// ------------------------------------------------- gather1: 2 lanes/node, int4 bulk indices
__global__ __launch_bounds__(256) void gather1_kernel(
        const unsigned* __restrict__ x8, const int* __restrict__ row_off,
        const int* __restrict__ degb, const int* __restrict__ csr,
        float* __restrict__ aggr, int N) {
    int t = threadIdx.x;
    int l = t >> 1, q = t & 1;
    int node = blockIdx.x * 128 + l;
    if (node >= N) return;
    int r0 = row_off[node];
    int dg = degb[node];
    int nv = (dg + 3) >> 2;
    const unsigned M = 0x00FF00FFu;
    unsigned Al = 0, Ah = 0;
    for (int i = 0; i < nv; i++) {
        int4 id4 = *(const int4*)(csr + r0 + i * 4);
        unsigned u0 = x8[(size_t)id4.x * 2 + q];
        unsigned u1 = x8[(size_t)id4.y * 2 + q];
        unsigned u2 = x8[(size_t)id4.z * 2 + q];
        unsigned u3 = x8[(size_t)id4.w * 2 + q];
        Al += u0 & M; Ah += (u0 >> 8) & M;
        Al += u1 & M; Ah += (u1 >> 8) & M;
        Al += u2 & M; Ah += (u2 >> 8) & M;
        Al += u3 & M; Ah += (u3 >> 8) & M;
    }
    float bias = 128.0f * (float)(4 * nv);              // pads are biased zeros
    float inv = 1.0f / (X8SCALE * fmaxf((float)dg, 1.0f));
    float4 o;
    o.x = ((float)(Al & 0xFFFF) - bias) * inv;
    o.y = ((float)(Ah & 0xFFFF) - bias) * inv;
    o.z = ((float)(Al >> 16) - bias) * inv;
    o.w = ((float)(Ah >> 16) - bias) * inv;
    ((float4*)(aggr + (size_t)node * IN_CH))[q] = o;
}

// ------------------------------------------------- dense1b: wave-uniform j-quarter split
__global__ __launch_bounds__(256) void dense1b_kernel(
        const float* __restrict__ x, const float* __restrict__ aggr,
        const float* __restrict__ b1, const float* __restrict__ b2,
        const unsigned* __restrict__ w1p, const unsigned* __restrict__ w2lp,
        const unsigned* __restrict__ w2rp,
        unsigned* __restrict__ p8, unsigned* __restrict__ selfh, int N) {
    int t = threadIdx.x;
    int w = t >> 6;                   // j-quarter 0..3 (wave-uniform)
    int lane = t & 63;
    int n = blockIdx.x * 64 + lane;
    if (n >= N) return;
    if (n == 0 && w == 0) {
        uint4 z = make_uint4(0x80808080u, 0x80808080u, 0x80808080u, 0x80808080u);
        ((uint4*)(p8 + (size_t)N * 8))[0] = z;
        ((uint4*)(p8 + (size_t)N * 8))[1] = z;
    }

    half2n uv[IN_CH];
    {
        float4 a0 = ((const float4*)(aggr + (size_t)n * IN_CH))[0];
        float4 a1 = ((const float4*)(aggr + (size_t)n * IN_CH))[1];
        float4 b0 = ((const float4*)(x + (size_t)n * IN_CH))[0];
        float4 b1v = ((const float4*)(x + (size_t)n * IN_CH))[1];
        uv[0] = mkh2(a0.x, b0.x); uv[1] = mkh2(a0.y, b0.y);
        uv[2] = mkh2(a0.z, b0.z); uv[3] = mkh2(a0.w, b0.w);
        uv[4] = mkh2(a1.x, b1v.x); uv[5] = mkh2(a1.y, b1v.y);
        uv[6] = mkh2(a1.z, b1v.z); uv[7] = mkh2(a1.w, b1v.w);
    }

    float pacc[8], sacc[8];
    const unsigned* w2lq = w2lp + w * 8;   // quarter base (wave-uniform)
    const unsigned* w2rq = w2rp + w * 8;
    #pragma unroll
    for (int j = 0; j < 8; j++) { pacc[j] = 0.0f; sacc[j] = b2[w * 8 + j]; }

    #pragma unroll 2
    for (int k2 = 0; k2 < HID / 2; k2++) {
        int k = 2 * k2;
        float h0 = b1[k], h1 = b1[k + 1];
        #pragma unroll
        for (int c = 0; c < IN_CH; c++) {
            h0 = fdot2w(uv[c], u2n(w1p[k * 8 + c]), h0);
            h1 = fdot2w(uv[c], u2n(w1p[(k + 1) * 8 + c]), h1);
        }
        h0 = fmaxf(h0, 0.0f);
        h1 = fmaxf(h1, 0.0f);
        half2n hh = mkh2(h0, h1);
        #pragma unroll
        for (int j = 0; j < 8; j++) {
            pacc[j] = fdot2w(hh, u2n(w2lq[k2 * EMB + j]), pacc[j]);
            sacc[j] = fdot2w(hh, u2n(w2rq[k2 * EMB + j]), sacc[j]);
        }
    }

    unsigned up[2];
    #pragma unroll
    for (int m = 0; m < 2; m++) {
        int q0 = min(127, max(-127, __float2int_rn(pacc[4 * m + 0] * P8SCALE)));
        int q1 = min(127, max(-127, __float2int_rn(pacc[4 * m + 1] * P8SCALE)));
        int q2 = min(127, max(-127, __float2int_rn(pacc[4 * m + 2] * P8SCALE)));
        int q3 = min(127, max(-127, __float2int_rn(pacc[4 * m + 3] * P8SCALE)));
        up[m] = ((unsigned)(q0 & 255) | ((unsigned)(q1 & 255) << 8)
              | ((unsigned)(q2 & 255) << 16) | ((unsigned)(q3 & 255) << 24)) ^ 0x80808080u;
    }
    ((uint2*)(p8 + (size_t)n * 8 + w * 2))[0] = make_uint2(up[0], up[1]);

    unsigned us[4];
    #pragma unroll
    for (int m = 0; m < 4; m++)
        us[m] = h22u(__floats2half2_rn(sacc[2 * m], sacc[2 * m + 1]));
    ((uint4*)(selfh + (size_t)n * 16 + w * 4))[0] = make_uint4(us[0], us[1], us[2], us[3]);
}

// ------------------------------------------------- gather2: 4 lanes/node, dual index streams
// lane (g,q): g = even/odd int4-quad stream, q = payload half (uint4 of 32B row).
// Doubles independent load chains per node at same request count. Final combine:
// one packed shfl_xor(2) add (exact: halfword sums <= 38k < 65535).
// 128 threads = 32 nodes/block -> 3125 blocks. Phase 2: thread-per-node head MLP.
__global__ __launch_bounds__(128) void gather2_kernel(
        const unsigned* __restrict__ p8, const unsigned* __restrict__ selfh,
        const int* __restrict__ row_off, const int* __restrict__ degb,
        const int* __restrict__ csr,
        const float* __restrict__ Wh1, const float* __restrict__ bh1,
        const float* __restrict__ Wh2, const float* __restrict__ bh2,
        float* __restrict__ out, int N) {
    __shared__ float zs[32 * 33];
    __shared__ float sW1[EMB * 16];
    __shared__ float sbh1[16];
    __shared__ float sW2[16];
    __shared__ float sbh2;
    int t = threadIdx.x;
    for (int i = t; i < EMB * 16; i += 128) sW1[i] = Wh1[i];
    if (t < 16) { sbh1[t] = bh1[t]; sW2[t] = Wh2[t]; }
    if (t == 0) sbh2 = bh2[0];

    int l = t >> 2;                  // local node 0..31
    int g = (t >> 1) & 1;            // quad stream 0/1
    int q = t & 1;                   // payload half
    int node = blockIdx.x * 32 + l;

    if (node < N) {
        int r0 = row_off[node];
        int dg = degb[node];
        int nv = (dg + 3) >> 2;
        const unsigned M = 0x00FF00FFu;
        unsigned A[8];
        #pragma unroll
        for (int j = 0; j < 8; j++) A[j] = 0;

        for (int i = g; i < nv; i += 2) {
            int4 id4 = *(const int4*)(csr + r0 + i * 4);
            uint4 u0 = *(const uint4*)(p8 + (size_t)id4.x * 8 + q * 4);
            uint4 u1 = *(const uint4*)(p8 + (size_t)id4.y * 8 + q * 4);
            uint4 u2 = *(const uint4*)(p8 + (size_t)id4.z * 8 + q * 4);
            uint4 u3 = *(const uint4*)(p8 + (size_t)id4.w * 8 + q * 4);
            A[0] += u0.x & M; A[1] += (u0.x >> 8) & M;
            A[2] += u0.y & M; A[3] += (u0.y >> 8) & M;
            A[4] += u0.z & M; A[5] += (u0.z >> 8) & M;
            A[6] += u0.w & M; A[7] += (u0.w >> 8) & M;
            A[0] += u1.x & M; A[1] += (u1.x >> 8) & M;
            A[2] += u1.y & M; A[3] += (u1.y >> 8) & M;
            A[4] += u1.z & M; A[5] += (u1.z >> 8) & M;
            A[6] += u1.w & M; A[7] += (u1.w >> 8) & M;
            A[0] += u2.x & M; A[1] += (u2.x >> 8) & M;
            A[2] += u2.y & M; A[3] += (u2.y >> 8) & M;
            A[4] += u2.z & M; A[5] += (u2.z >> 8) & M;
            A[6] += u2.w & M; A[7] += (u2.w >> 8) & M;
            A[0] += u3.x & M; A[1] += (u3.x >> 8) & M;
            A[2] += u3.y & M; A[3] += (u3.y >> 8) & M;
            A[4] += u3.z & M; A[5] += (u3.z >> 8) & M;
            A[6] += u3.w & M; A[7] += (u3.w >> 8) & M;
        }

        // combine the two quad streams (lanes differ in bit 1)
        #pragma unroll
        for (int j = 0; j < 8; j++)
            A[j] += (unsigned)__shfl_xor((int)A[j], 2);

        float bias = 128.0f * (float)(4 * nv);          // pads are biased zeros
        float sc = (1.0f / P8SCALE) / fmaxf((float)dg, 1.0f);
        const uint4* sb = (const uint4*)(selfh + (size_t)node * 16 + q * 8);
        uint4 s0 = sb[0], s1 = sb[1];
        float sf[16];
        { float2 c = __half22float2(u2h2(s0.x)); sf[0] = c.x; sf[1] = c.y; }
        { float2 c = __half22float2(u2h2(s0.y)); sf[2] = c.x; sf[3] = c.y; }
        { float2 c = __half22float2(u2h2(s0.z)); sf[4] = c.x; sf[5] = c.y; }
        { float2 c = __half22float2(u2h2(s0.w)); sf[6] = c.x; sf[7] = c.y; }
        { float2 c = __half22float2(u2h2(s1.x)); sf[8] = c.x; sf[9] = c.y; }
        { float2 c = __half22float2(u2h2(s1.y)); sf[10] = c.x; sf[11] = c.y; }
        { float2 c = __half22float2(u2h2(s1.z)); sf[12] = c.x; sf[13] = c.y; }
        { float2 c = __half22float2(u2h2(s1.w)); sf[14] = c.x; sf[15] = c.y; }

        if (g == 0) {
            float* zrow = zs + l * 33 + q * 16;
            #pragma unroll
            for (int w = 0; w < 4; w++) {
                float c0 = ((float)(A[2 * w] & 0xFFFF) - bias) * sc;
                float c1 = ((float)(A[2 * w + 1] & 0xFFFF) - bias) * sc;
                float c2 = ((float)(A[2 * w] >> 16) - bias) * sc;
                float c3 = ((float)(A[2 * w + 1] >> 16) - bias) * sc;
                zrow[4 * w + 0] = fmaxf(c0 + sf[4 * w + 0], 0.0f);
                zrow[4 * w + 1] = fmaxf(c1 + sf[4 * w + 1], 0.0f);
                zrow[4 * w + 2] = fmaxf(c2 + sf[4 * w + 2], 0.0f);
                zrow[4 * w + 3] = fmaxf(c3 + sf[4 * w + 3], 0.0f);
            }
        }
    }
    __syncthreads();

    if (t < 32) {
        int node2 = blockIdx.x * 32 + t;
        if (node2 < N) {
            float zr[EMB];
            #pragma unroll
            for (int k = 0; k < EMB; k++) zr[k] = zs[t * 33 + k];
            float logit = sbh2;
            #pragma unroll
            for (int i = 0; i < 16; i++) {
                float acc = sbh1[i];
                #pragma unroll
                for (int k = 0; k < EMB; k++) acc += zr[k] * sW1[k * 16 + i];
                logit += fmaxf(acc, 0.0f) * sW2[i];
            }
            out[node2] = 1.0f / (1.0f + expf(-logit));
        }
    }
}

// ---------------------------------------------------------------- launch
extern "C" void kernel_launch(void* const* d_in, const int* in_sizes, int n_in,
                              void* d_out, int out_size, void* d_ws, size_t ws_size,
                              hipStream_t stream) {
    const float* x   = (const float*)d_in[0];
    const int*   ei  = (const int*)d_in[1];
    const float* W1l = (const float*)d_in[2];
    const float* b1  = (const float*)d_in[3];
    const float* W1r = (const float*)d_in[4];
    const float* W2l = (const float*)d_in[5];
    const float* b2  = (const float*)d_in[6];
    const float* W2r = (const float*)d_in[7];
    const float* Wh1 = (const float*)d_in[8];
    const float* bh1 = (const float*)d_in[9];
    const float* Wh2 = (const float*)d_in[10];
    const float* bh2 = (const float*)d_in[11];

    int N = in_sizes[0] / IN_CH;     // 100000
    int E = in_sizes[1] / 2;         // 3200000
    int NB = (N + BW - 1) / BW;      // 196 buckets
    int M  = NB * HBLK;              // blkoff cells
    int per = (((E + HBLK - 1) / HBLK) + 3) & ~3;   // per-block edge span, x4 aligned
    int CSRSZ = E + (NB + 1) * PSTRIDE;             // padded CSR capacity
    int PB = (N + 255) / 256;                       // prep blocks

    // workspace layout (all segments x4-int aligned):
    // [staged E][blkoff M][gcnt NB4][sbase NB4+4][row_off N4][degb N4][csr CSRSZ]
    // [x8 2(N+2)][aggr 8N f32][selfh 16N][p8 8(N+1)+pad][w1p 512][w2lp 1024][w2rp 1024]
    int N4 = (N + 3) & ~3;
    int NB4 = (NB + 3) & ~3;
    int* staged   = (int*)d_ws;
    int* blkoff   = staged + E;                     // E mult of 4
    int* gcnt     = blkoff + M;                     // M mult of 4
    int* sbase    = gcnt + NB4;
    int* row_off  = sbase + NB4 + 4;
    int* degb     = row_off + N4;
    int* csr      = degb + N4;
    unsigned* x8  = (unsigned*)(csr + CSRSZ);       // CSRSZ mult of 4
    float* aggr   = (float*)(x8 + (size_t)(N + 2) * 2);
    unsigned* selfh = (unsigned*)(aggr + (size_t)N * IN_CH);
    unsigned* p8  = selfh + (size_t)N * 16;
    unsigned* w1p = p8 + (size_t)(N + 1) * 8 + 4;   // keep x4 alignment
    unsigned* w2lp = w1p + HID * IN_CH;
    unsigned* w2rp = w2lp + (HID / 2) * EMB;

    (void)hipMemsetAsync(gcnt, 0, sizeof(int) * NB4, stream);
    histprep_kernel<<<HBLK + PB, 256, 0, stream>>>(ei, gcnt, blkoff, E, NB, per,
                                                   x, x8, W1l, W1r, W2l, W2r,
                                                   w1p, w2lp, w2rp, N);
    bscan_kernel  <<<1, 256, 0, stream>>>(gcnt, sbase, E, NB);
    scat_kernel   <<<HBLK, 256, 0, stream>>>(ei, sbase, blkoff, staged, E, NB, per);
    bucket_kernel <<<NB, 512, 0, stream>>>(staged, sbase, row_off, degb, csr, N, E, NB);
    gather1_kernel<<<(N + 127) / 128, 256, 0, stream>>>(x8, row_off, degb, csr, aggr, N);
    dense1b_kernel<<<(N + 63) / 64, 256, 0, stream>>>(x, aggr, b1, b2,
                                                      w1p, w2lp, w2rp, p8, selfh, N);
    gather2_kernel<<<(N + 31) / 32, 128, 0, stream>>>(p8, selfh, row_off, degb, csr,
                                                      Wh1, bh1, Wh2, bh2, (float*)d_out, N);
}

// Round 21
// 123.273 us; speedup vs baseline: 1.4191x; 1.2490x over previous
//
#include <hip/hip_runtime.h>
#include <hip/hip_fp16.h>
#include <math.h>

#define IN_CH 8
#define HID   64
#define EMB   32
#define HBLK  256       // blocks in hist/scatter phases
#define BW    512       // nodes per bucket (dst >> 9)
#define BSH   9         // log2(BW)
#define NBMAX 256       // max buckets supported (N <= 131072)
#define P8SCALE 128.0f
#define X8SCALE 16.0f

typedef _Float16 half2n __attribute__((ext_vector_type(2)));

static __device__ __forceinline__ __half2 u2h2(unsigned u) {
    union { unsigned u; __half2 h; } c; c.u = u; return c.h;
}
static __device__ __forceinline__ unsigned h22u(__half2 h) {
    union { unsigned u; __half2 h; } c; c.h = h; return c.u;
}
static __device__ __forceinline__ half2n u2n(unsigned u) {
    union { unsigned u; half2n h; } c; c.u = u; return c.h;
}
static __device__ __forceinline__ half2n mkh2(float a, float b) {
    half2n r; r.x = (_Float16)a; r.y = (_Float16)b; return r;
}
static __device__ __forceinline__ float fdot2w(half2n a, half2n b, float c) {
#if __has_builtin(__builtin_amdgcn_fdot2)
    return __builtin_amdgcn_fdot2(a, b, c, false);
#else
    return (float)a.x * (float)b.x + (float)a.y * (float)b.y + c;
#endif
}

// ------------------------------------------------- fused hist + prep
// blocks [0, HBLK): per-block bucket histogram (ILP-4), commit offsets via atomic.
// blocks [HBLK, ...): x -> biased int8 rows; block HBLK additionally packs weights.
__global__ __launch_bounds__(256) void histprep_kernel(
        const int* __restrict__ ei, int* __restrict__ gcnt, int* __restrict__ blkoff,
        int E, int NB, int per,
        const float* __restrict__ x, unsigned* __restrict__ x8,
        const float* __restrict__ W1l, const float* __restrict__ W1r,
        const float* __restrict__ W2l, const float* __restrict__ W2r,
        unsigned* __restrict__ w1p, unsigned* __restrict__ w2lp,
        unsigned* __restrict__ w2rp, int N) {
    __shared__ int lh[NBMAX];
    int b = blockIdx.x, t = threadIdx.x;
    if (b < HBLK) {
        for (int i = t; i < NB; i += 256) lh[i] = 0;
        __syncthreads();
        int e0 = b * per, e1 = min(e0 + per, E);
        if (e0 < e1) {
            if ((E & 3) == 0) {
                int nv = (e1 - e0) >> 2;
                for (int g = t; g < nv; g += 256) {
                    int4 d = *(const int4*)(ei + E + e0 + g * 4);
                    atomicAdd(&lh[d.x >> BSH], 1);
                    atomicAdd(&lh[d.y >> BSH], 1);
                    atomicAdd(&lh[d.z >> BSH], 1);
                    atomicAdd(&lh[d.w >> BSH], 1);
                }
                for (int e = e0 + nv * 4 + t; e < e1; e += 256)
                    atomicAdd(&lh[ei[E + e] >> BSH], 1);
            } else {
                for (int e = e0 + t; e < e1; e += 256)
                    atomicAdd(&lh[ei[E + e] >> BSH], 1);
            }
        }
        __syncthreads();
        for (int i = t; i < NB; i += 256)
            blkoff[b * NB + i] = atomicAdd(&gcnt[i], lh[i]);
        return;
    }
    // ---- prep branch
    int pb = b - HBLK;
    if (pb == 0) {
        for (int i = t; i < HID * IN_CH; i += 256) {
            int k = i >> 3, c = i & 7;
            w1p[i] = h22u(__floats2half2_rn(W1l[c * HID + k], W1r[c * HID + k]));
        }
        for (int i = t; i < (HID / 2) * EMB; i += 256) {
            int k2 = i >> 5, j = i & 31;
            w2lp[i] = h22u(__floats2half2_rn(W2l[(2 * k2) * EMB + j], W2l[(2 * k2 + 1) * EMB + j]));
            w2rp[i] = h22u(__floats2half2_rn(W2r[(2 * k2) * EMB + j], W2r[(2 * k2 + 1) * EMB + j]));
        }
    }
    int n = pb * 256 + t;
    if (n >= N) return;
    float4 a = ((const float4*)(x + (size_t)n * IN_CH))[0];
    float4 bb = ((const float4*)(x + (size_t)n * IN_CH))[1];
    float v[8] = {a.x, a.y, a.z, a.w, bb.x, bb.y, bb.z, bb.w};
    unsigned w0 = 0, w1 = 0;
    #pragma unroll
    for (int c = 0; c < 4; c++) {
        int q = min(127, max(-127, __float2int_rn(v[c] * X8SCALE))) + 128;
        w0 |= ((unsigned)q) << (8 * c);
    }
    #pragma unroll
    for (int c = 0; c < 4; c++) {
        int q = min(127, max(-127, __float2int_rn(v[4 + c] * X8SCALE))) + 128;
        w1 |= ((unsigned)q) << (8 * c);
    }
    ((uint2*)(x8 + (size_t)n * 2))[0] = make_uint2(w0, w1);
}

// ------------------------------------------------- bscan: 1 block, exclusive scan of NB counts
__global__ __launch_bounds__(256) void bscan_kernel(const int* __restrict__ gcnt,
                                                    int* __restrict__ sbase, int E, int NB) {
    __shared__ int bsum[256];
    int t = threadIdx.x;
    bsum[t] = (t < NB) ? gcnt[t] : 0;
    __syncthreads();
    for (int off = 1; off < 256; off <<= 1) {
        int v = (t >= off) ? bsum[t - off] : 0;
        __syncthreads();
        bsum[t] += v;
        __syncthreads();
    }
    if (t < NB) sbase[t] = bsum[t] - gcnt[t];
    if (t == 0) sbase[NB] = E;
}

// ------------------------------------------------- scat: scatter edges (packed src|li), ILP-4
__global__ __launch_bounds__(256) void scat_kernel(const int* __restrict__ ei,
                                                   const int* __restrict__ sbase,
                                                   const int* __restrict__ blkoff,
                                                   int* __restrict__ staged, int E, int NB,
                                                   int per) {
    __shared__ int lcur[NBMAX];
    int b = blockIdx.x, t = threadIdx.x;
    for (int i = t; i < NB; i += 256) lcur[i] = sbase[i] + blkoff[b * NB + i];
    __syncthreads();
    int e0 = b * per, e1 = min(e0 + per, E);
    if (e0 >= e1) return;
    if ((E & 3) == 0) {
        int nv = (e1 - e0) >> 2;
        for (int g = t; g < nv; g += 256) {
            int e = e0 + g * 4;
            int4 s4 = *(const int4*)(ei + e);
            int4 d4 = *(const int4*)(ei + E + e);
            int p0 = atomicAdd(&lcur[d4.x >> BSH], 1);
            staged[p0] = s4.x | ((d4.x & (BW - 1)) << 17);
            int p1 = atomicAdd(&lcur[d4.y >> BSH], 1);
            staged[p1] = s4.y | ((d4.y & (BW - 1)) << 17);
            int p2 = atomicAdd(&lcur[d4.z >> BSH], 1);
            staged[p2] = s4.z | ((d4.z & (BW - 1)) << 17);
            int p3 = atomicAdd(&lcur[d4.w >> BSH], 1);
            staged[p3] = s4.w | ((d4.w & (BW - 1)) << 17);
        }
        for (int e = e0 + nv * 4 + t; e < e1; e += 256) {
            int src = ei[e], dst = ei[E + e];
            int pos = atomicAdd(&lcur[dst >> BSH], 1);
            staged[pos] = src | ((dst & (BW - 1)) << 17);
        }
    } else {
        for (int e = e0 + t; e < e1; e += 256) {
            int src = ei[e], dst = ei[E + e];
            int pos = atomicAdd(&lcur[dst >> BSH], 1);
            staged[pos] = src | ((dst & (BW - 1)) << 17);
        }
    }
}

// ------------------------------------------------- bagg1: bucket-LDS layer-1 aggregate
// Block per bucket: stream staged segment; per edge 2 uint x8 loads + 4 native
// ds_add_u32 (packed-u16, exact) + degree add. Finalize thread-per-node -> aggr, degb.
__global__ __launch_bounds__(512) void bagg1_kernel(
        const int* __restrict__ staged, const int* __restrict__ sbase,
        const unsigned* __restrict__ x8,
        float* __restrict__ aggr, int* __restrict__ degb, int N, int NB) {
    __shared__ unsigned xs[BW * 5];   // stride 5 (4 accum u32 + pad)
    __shared__ int ldeg[BW];
    int b = blockIdx.x, t = threadIdx.x;
    int base = b * BW;
    int s0 = sbase[b], s1 = sbase[b + 1];

    for (int i = t; i < BW * 5; i += 512) xs[i] = 0u;
    ldeg[t] = 0;
    __syncthreads();

    const unsigned M = 0x00FF00FFu;
    for (int e = s0 + t; e < s1; e += 512) {
        int v = staged[e];
        int li = v >> 17;
        int src = v & 0x1FFFF;
        uint2 u = *(const uint2*)(x8 + (size_t)src * 2);
        unsigned* xp = xs + li * 5;
        atomicAdd(xp + 0, u.x & M);
        atomicAdd(xp + 1, (u.x >> 8) & M);
        atomicAdd(xp + 2, u.y & M);
        atomicAdd(xp + 3, (u.y >> 8) & M);
        atomicAdd(&ldeg[li], 1);
    }
    __syncthreads();

    int node = base + t;
    if (node >= N) return;
    int dg = ldeg[t];
    float bias = 128.0f * (float)dg;
    float inv = 1.0f / (X8SCALE * fmaxf((float)dg, 1.0f));
    unsigned Al0 = xs[t * 5 + 0], Ah0 = xs[t * 5 + 1];
    unsigned Al1 = xs[t * 5 + 2], Ah1 = xs[t * 5 + 3];
    float4 o0, o1;
    o0.x = ((float)(Al0 & 0xFFFF) - bias) * inv;
    o0.y = ((float)(Ah0 & 0xFFFF) - bias) * inv;
    o0.z = ((float)(Al0 >> 16) - bias) * inv;
    o0.w = ((float)(Ah0 >> 16) - bias) * inv;
    o1.x = ((float)(Al1 & 0xFFFF) - bias) * inv;
    o1.y = ((float)(Ah1 & 0xFFFF) - bias) * inv;
    o1.z = ((float)(Al1 >> 16) - bias) * inv;
    o1.w = ((float)(Ah1 >> 16) - bias) * inv;
    ((float4*)(aggr + (size_t)node * IN_CH))[0] = o0;
    ((float4*)(aggr + (size_t)node * IN_CH))[1] = o1;
    degb[node] = dg;
}

// ------------------------------------------------- dense1b: wave-uniform j-quarter split
__global__ __launch_bounds__(256) void dense1b_kernel(
        const float* __restrict__ x, const float* __restrict__ aggr,
        const float* __restrict__ b1, const float* __restrict__ b2,
        const unsigned* __restrict__ w1p, const unsigned* __restrict__ w2lp,
        const unsigned* __restrict__ w2rp,
        unsigned* __restrict__ p8, unsigned* __restrict__ selfh, int N) {
    int t = threadIdx.x;
    int w = t >> 6;                   // j-quarter 0..3 (wave-uniform)
    int lane = t & 63;
    int n = blockIdx.x * 64 + lane;
    if (n >= N) return;

    half2n uv[IN_CH];
    {
        float4 a0 = ((const float4*)(aggr + (size_t)n * IN_CH))[0];
        float4 a1 = ((const float4*)(aggr + (size_t)n * IN_CH))[1];
        float4 b0 = ((const float4*)(x + (size_t)n * IN_CH))[0];
        float4 b1v = ((const float4*)(x + (size_t)n * IN_CH))[1];
        uv[0] = mkh2(a0.x, b0.x); uv[1] = mkh2(a0.y, b0.y);
        uv[2] = mkh2(a0.z, b0.z); uv[3] = mkh2(a0.w, b0.w);
        uv[4] = mkh2(a1.x, b1v.x); uv[5] = mkh2(a1.y, b1v.y);
        uv[6] = mkh2(a1.z, b1v.z); uv[7] = mkh2(a1.w, b1v.w);
    }

    float pacc[8], sacc[8];
    const unsigned* w2lq = w2lp + w * 8;   // quarter base (wave-uniform)
    const unsigned* w2rq = w2rp + w * 8;
    #pragma unroll
    for (int j = 0; j < 8; j++) { pacc[j] = 0.0f; sacc[j] = b2[w * 8 + j]; }

    #pragma unroll 2
    for (int k2 = 0; k2 < HID / 2; k2++) {
        int k = 2 * k2;
        float h0 = b1[k], h1 = b1[k + 1];
        #pragma unroll
        for (int c = 0; c < IN_CH; c++) {
            h0 = fdot2w(uv[c], u2n(w1p[k * 8 + c]), h0);
            h1 = fdot2w(uv[c], u2n(w1p[(k + 1) * 8 + c]), h1);
        }
        h0 = fmaxf(h0, 0.0f);
        h1 = fmaxf(h1, 0.0f);
        half2n hh = mkh2(h0, h1);
        #pragma unroll
        for (int j = 0; j < 8; j++) {
            pacc[j] = fdot2w(hh, u2n(w2lq[k2 * EMB + j]), pacc[j]);
            sacc[j] = fdot2w(hh, u2n(w2rq[k2 * EMB + j]), sacc[j]);
        }
    }

    unsigned up[2];
    #pragma unroll
    for (int m = 0; m < 2; m++) {
        int q0 = min(127, max(-127, __float2int_rn(pacc[4 * m + 0] * P8SCALE)));
        int q1 = min(127, max(-127, __float2int_rn(pacc[4 * m + 1] * P8SCALE)));
        int q2 = min(127, max(-127, __float2int_rn(pacc[4 * m + 2] * P8SCALE)));
        int q3 = min(127, max(-127, __float2int_rn(pacc[4 * m + 3] * P8SCALE)));
        up[m] = ((unsigned)(q0 & 255) | ((unsigned)(q1 & 255) << 8)
              | ((unsigned)(q2 & 255) << 16) | ((unsigned)(q3 & 255) << 24)) ^ 0x80808080u;
    }
    ((uint2*)(p8 + (size_t)n * 8 + w * 2))[0] = make_uint2(up[0], up[1]);

    unsigned us[4];
    #pragma unroll
    for (int m = 0; m < 4; m++)
        us[m] = h22u(__floats2half2_rn(sacc[2 * m], sacc[2 * m + 1]));
    ((uint4*)(selfh + (size_t)n * 16 + w * 4))[0] = make_uint4(us[0], us[1], us[2], us[3]);
}

// ------------------------------------------------- bagg2: bucket-LDS layer-2 aggregate + head
// Block per bucket: stream staged; per edge 8-uint p8 row + 16 native ds_add_u32
// (packed-u16, exact). Finalize thread-per-node: unbias + self + relu + head MLP
// (wave-uniform scalar weights) + sigmoid -> out.
__global__ __launch_bounds__(512) void bagg2_kernel(
        const int* __restrict__ staged, const int* __restrict__ sbase,
        const unsigned* __restrict__ p8, const unsigned* __restrict__ selfh,
        const int* __restrict__ degb,
        const float* __restrict__ Wh1, const float* __restrict__ bh1,
        const float* __restrict__ Wh2, const float* __restrict__ bh2,
        float* __restrict__ out, int N, int NB) {
    __shared__ unsigned zs[BW * 17];  // 16 accum u32 per node + pad
    int b = blockIdx.x, t = threadIdx.x;
    int base = b * BW;
    int s0 = sbase[b], s1 = sbase[b + 1];

    for (int i = t; i < BW * 17; i += 512) zs[i] = 0u;
    __syncthreads();

    const unsigned M = 0x00FF00FFu;
    for (int e = s0 + t; e < s1; e += 512) {
        int v = staged[e];
        int li = v >> 17;
        int src = v & 0x1FFFF;
        uint4 a = ((const uint4*)(p8 + (size_t)src * 8))[0];
        uint4 c = ((const uint4*)(p8 + (size_t)src * 8))[1];
        unsigned* zp = zs + li * 17;
        atomicAdd(zp + 0, a.x & M);  atomicAdd(zp + 1, (a.x >> 8) & M);
        atomicAdd(zp + 2, a.y & M);  atomicAdd(zp + 3, (a.y >> 8) & M);
        atomicAdd(zp + 4, a.z & M);  atomicAdd(zp + 5, (a.z >> 8) & M);
        atomicAdd(zp + 6, a.w & M);  atomicAdd(zp + 7, (a.w >> 8) & M);
        atomicAdd(zp + 8, c.x & M);  atomicAdd(zp + 9, (c.x >> 8) & M);
        atomicAdd(zp + 10, c.y & M); atomicAdd(zp + 11, (c.y >> 8) & M);
        atomicAdd(zp + 12, c.z & M); atomicAdd(zp + 13, (c.z >> 8) & M);
        atomicAdd(zp + 14, c.w & M); atomicAdd(zp + 15, (c.w >> 8) & M);
    }
    __syncthreads();

    int node = base + t;
    if (node >= N) return;
    int dg = degb[node];
    float bias = 128.0f * (float)dg;
    float sc = (1.0f / P8SCALE) / fmaxf((float)dg, 1.0f);

    float z[EMB];
    const uint4* sb = (const uint4*)(selfh + (size_t)node * 16);
    #pragma unroll
    for (int j = 0; j < 8; j++) {          // row uint j: channels 4j..4j+3
        unsigned lo = zs[t * 17 + 2 * j];
        unsigned hi = zs[t * 17 + 2 * j + 1];
        uint2 sh = ((const uint2*)sb)[j];
        float2 c0 = __half22float2(u2h2(sh.x));
        float2 c1 = __half22float2(u2h2(sh.y));
        z[4 * j + 0] = fmaxf(((float)(lo & 0xFFFF) - bias) * sc + c0.x, 0.0f);
        z[4 * j + 1] = fmaxf(((float)(hi & 0xFFFF) - bias) * sc + c0.y, 0.0f);
        z[4 * j + 2] = fmaxf(((float)(lo >> 16) - bias) * sc + c1.x, 0.0f);
        z[4 * j + 3] = fmaxf(((float)(hi >> 16) - bias) * sc + c1.y, 0.0f);
    }

    float logit = bh2[0];
    #pragma unroll
    for (int i = 0; i < 16; i++) {
        float acc = bh1[i];
        #pragma unroll
        for (int k = 0; k < EMB; k++) acc += z[k] * Wh1[k * 16 + i];
        logit += fmaxf(acc, 0.0f) * Wh2[i];
    }
    out[node] = 1.0f / (1.0f + expf(-logit));
}

// ---------------------------------------------------------------- launch
extern "C" void kernel_launch(void* const* d_in, const int* in_sizes, int n_in,
                              void* d_out, int out_size, void* d_ws, size_t ws_size,
                              hipStream_t stream) {
    const float* x   = (const float*)d_in[0];
    const int*   ei  = (const int*)d_in[1];
    const float* W1l = (const float*)d_in[2];
    const float* b1  = (const float*)d_in[3];
    const float* W1r = (const float*)d_in[4];
    const float* W2l = (const float*)d_in[5];
    const float* b2  = (const float*)d_in[6];
    const float* W2r = (const float*)d_in[7];
    const float* Wh1 = (const float*)d_in[8];
    const float* bh1 = (const float*)d_in[9];
    const float* Wh2 = (const float*)d_in[10];
    const float* bh2 = (const float*)d_in[11];

    int N = in_sizes[0] / IN_CH;     // 100000
    int E = in_sizes[1] / 2;         // 3200000
    int NB = (N + BW - 1) / BW;      // 196 buckets
    int M  = NB * HBLK;              // blkoff cells
    int per = (((E + HBLK - 1) / HBLK) + 3) & ~3;   // per-block edge span, x4 aligned
    int PB = (N + 255) / 256;                       // prep blocks

    // workspace layout (all segments x4-int aligned):
    // [staged E][blkoff M][gcnt NB4][sbase NB4+4][degb N4]
    // [x8 2(N+2)][aggr 8N f32][selfh 16N][p8 8(N+1)][w1p 512][w2lp 1024][w2rp 1024]
    int N4 = (N + 3) & ~3;
    int NB4 = (NB + 3) & ~3;
    int* staged   = (int*)d_ws;
    int* blkoff   = staged + E;                     // E mult of 4
    int* gcnt     = blkoff + M;                     // M mult of 4
    int* sbase    = gcnt + NB4;
    int* degb     = sbase + NB4 + 4;
    unsigned* x8  = (unsigned*)(degb + N4);
    float* aggr   = (float*)(x8 + (size_t)(N + 2) * 2);
    unsigned* selfh = (unsigned*)(aggr + (size_t)N * IN_CH);
    unsigned* p8  = selfh + (size_t)N * 16;
    unsigned* w1p = p8 + (size_t)(N + 1) * 8 + 4;   // keep x4 alignment
    unsigned* w2lp = w1p + HID * IN_CH;
    unsigned* w2rp = w2lp + (HID / 2) * EMB;

    (void)hipMemsetAsync(gcnt, 0, sizeof(int) * NB4, stream);
    histprep_kernel<<<HBLK + PB, 256, 0, stream>>>(ei, gcnt, blkoff, E, NB, per,
                                                   x, x8, W1l, W1r, W2l, W2r,
                                                   w1p, w2lp, w2rp, N);
    bscan_kernel  <<<1, 256, 0, stream>>>(gcnt, sbase, E, NB);
    scat_kernel   <<<HBLK, 256, 0, stream>>>(ei, sbase, blkoff, staged, E, NB, per);
    bagg1_kernel  <<<NB, 512, 0, stream>>>(staged, sbase, x8, aggr, degb, N, NB);
    dense1b_kernel<<<(N + 63) / 64, 256, 0, stream>>>(x, aggr, b1, b2,
                                                      w1p, w2lp, w2rp, p8, selfh, N);
    bagg2_kernel  <<<NB, 512, 0, stream>>>(staged, sbase, p8, selfh, degb,
                                           Wh1, bh1, Wh2, bh2, (float*)d_out, N, NB);
}

// Round 22
// 119.234 us; speedup vs baseline: 1.4672x; 1.0339x over previous
//
#include <hip/hip_runtime.h>
#include <hip/hip_fp16.h>
#include <math.h>

#define IN_CH 8
#define HID   64
#define EMB   32
#define HBLK  256       // blocks in hist/scatter phases
#define BW    512       // nodes per bucket (dst >> 9)
#define BSH   9         // log2(BW)
#define NBMAX 256       // max buckets supported (N <= 131072)
#define P8SCALE 128.0f
#define X8SCALE 16.0f

typedef _Float16 half2n __attribute__((ext_vector_type(2)));

static __device__ __forceinline__ __half2 u2h2(unsigned u) {
    union { unsigned u; __half2 h; } c; c.u = u; return c.h;
}
static __device__ __forceinline__ unsigned h22u(__half2 h) {
    union { unsigned u; __half2 h; } c; c.h = h; return c.u;
}
static __device__ __forceinline__ half2n u2n(unsigned u) {
    union { unsigned u; half2n h; } c; c.u = u; return c.h;
}
static __device__ __forceinline__ half2n mkh2(float a, float b) {
    half2n r; r.x = (_Float16)a; r.y = (_Float16)b; return r;
}
static __device__ __forceinline__ float fdot2w(half2n a, half2n b, float c) {
#if __has_builtin(__builtin_amdgcn_fdot2)
    return __builtin_amdgcn_fdot2(a, b, c, false);
#else
    return (float)a.x * (float)b.x + (float)a.y * (float)b.y + c;
#endif
}

// ------------------------------------------------- fused hist + prep
__global__ __launch_bounds__(256) void histprep_kernel(
        const int* __restrict__ ei, int* __restrict__ gcnt, int* __restrict__ blkoff,
        int E, int NB, int per,
        const float* __restrict__ x, unsigned* __restrict__ x8,
        const float* __restrict__ W1l, const float* __restrict__ W1r,
        const float* __restrict__ W2l, const float* __restrict__ W2r,
        unsigned* __restrict__ w1p, unsigned* __restrict__ w2lp,
        unsigned* __restrict__ w2rp, int N) {
    __shared__ int lh[NBMAX];
    int b = blockIdx.x, t = threadIdx.x;
    if (b < HBLK) {
        for (int i = t; i < NB; i += 256) lh[i] = 0;
        __syncthreads();
        int e0 = b * per, e1 = min(e0 + per, E);
        if (e0 < e1) {
            if ((E & 3) == 0) {
                int nv = (e1 - e0) >> 2;
                for (int g = t; g < nv; g += 256) {
                    int4 d = *(const int4*)(ei + E + e0 + g * 4);
                    atomicAdd(&lh[d.x >> BSH], 1);
                    atomicAdd(&lh[d.y >> BSH], 1);
                    atomicAdd(&lh[d.z >> BSH], 1);
                    atomicAdd(&lh[d.w >> BSH], 1);
                }
                for (int e = e0 + nv * 4 + t; e < e1; e += 256)
                    atomicAdd(&lh[ei[E + e] >> BSH], 1);
            } else {
                for (int e = e0 + t; e < e1; e += 256)
                    atomicAdd(&lh[ei[E + e] >> BSH], 1);
            }
        }
        __syncthreads();
        for (int i = t; i < NB; i += 256)
            blkoff[b * NB + i] = atomicAdd(&gcnt[i], lh[i]);
        return;
    }
    // ---- prep branch
    int pb = b - HBLK;
    if (pb == 0) {
        for (int i = t; i < HID * IN_CH; i += 256) {
            int k = i >> 3, c = i & 7;
            w1p[i] = h22u(__floats2half2_rn(W1l[c * HID + k], W1r[c * HID + k]));
        }
        for (int i = t; i < (HID / 2) * EMB; i += 256) {
            int k2 = i >> 5, j = i & 31;
            w2lp[i] = h22u(__floats2half2_rn(W2l[(2 * k2) * EMB + j], W2l[(2 * k2 + 1) * EMB + j]));
            w2rp[i] = h22u(__floats2half2_rn(W2r[(2 * k2) * EMB + j], W2r[(2 * k2 + 1) * EMB + j]));
        }
    }
    int n = pb * 256 + t;
    if (n >= N) return;
    float4 a = ((const float4*)(x + (size_t)n * IN_CH))[0];
    float4 bb = ((const float4*)(x + (size_t)n * IN_CH))[1];
    float v[8] = {a.x, a.y, a.z, a.w, bb.x, bb.y, bb.z, bb.w};
    unsigned w0 = 0, w1 = 0;
    #pragma unroll
    for (int c = 0; c < 4; c++) {
        int q = min(127, max(-127, __float2int_rn(v[c] * X8SCALE))) + 128;
        w0 |= ((unsigned)q) << (8 * c);
    }
    #pragma unroll
    for (int c = 0; c < 4; c++) {
        int q = min(127, max(-127, __float2int_rn(v[4 + c] * X8SCALE))) + 128;
        w1 |= ((unsigned)q) << (8 * c);
    }
    ((uint2*)(x8 + (size_t)n * 2))[0] = make_uint2(w0, w1);
}

// ------------------------------------------------- bscan: 1 block, exclusive scan of NB counts
__global__ __launch_bounds__(256) void bscan_kernel(const int* __restrict__ gcnt,
                                                    int* __restrict__ sbase, int E, int NB) {
    __shared__ int bsum[256];
    int t = threadIdx.x;
    bsum[t] = (t < NB) ? gcnt[t] : 0;
    __syncthreads();
    for (int off = 1; off < 256; off <<= 1) {
        int v = (t >= off) ? bsum[t - off] : 0;
        __syncthreads();
        bsum[t] += v;
        __syncthreads();
    }
    if (t < NB) sbase[t] = bsum[t] - gcnt[t];
    if (t == 0) sbase[NB] = E;
}

// ------------------------------------------------- scat: scatter edges, 512 threads, ILP-4
__global__ __launch_bounds__(512) void scat_kernel(const int* __restrict__ ei,
                                                   const int* __restrict__ sbase,
                                                   const int* __restrict__ blkoff,
                                                   int* __restrict__ staged, int E, int NB,
                                                   int per) {
    __shared__ int lcur[NBMAX];
    int b = blockIdx.x, t = threadIdx.x;
    for (int i = t; i < NB; i += 512) lcur[i] = sbase[i] + blkoff[b * NB + i];
    __syncthreads();
    int e0 = b * per, e1 = min(e0 + per, E);
    if (e0 >= e1) return;
    if ((E & 3) == 0) {
        int nv = (e1 - e0) >> 2;
        for (int g = t; g < nv; g += 512) {
            int e = e0 + g * 4;
            int4 s4 = *(const int4*)(ei + e);
            int4 d4 = *(const int4*)(ei + E + e);
            int p0 = atomicAdd(&lcur[d4.x >> BSH], 1);
            staged[p0] = s4.x | ((d4.x & (BW - 1)) << 17);
            int p1 = atomicAdd(&lcur[d4.y >> BSH], 1);
            staged[p1] = s4.y | ((d4.y & (BW - 1)) << 17);
            int p2 = atomicAdd(&lcur[d4.z >> BSH], 1);
            staged[p2] = s4.z | ((d4.z & (BW - 1)) << 17);
            int p3 = atomicAdd(&lcur[d4.w >> BSH], 1);
            staged[p3] = s4.w | ((d4.w & (BW - 1)) << 17);
        }
        for (int e = e0 + nv * 4 + t; e < e1; e += 512) {
            int src = ei[e], dst = ei[E + e];
            int pos = atomicAdd(&lcur[dst >> BSH], 1);
            staged[pos] = src | ((dst & (BW - 1)) << 17);
        }
    } else {
        for (int e = e0 + t; e < e1; e += 512) {
            int src = ei[e], dst = ei[E + e];
            int pos = atomicAdd(&lcur[dst >> BSH], 1);
            staged[pos] = src | ((dst & (BW - 1)) << 17);
        }
    }
}

// ------------------------------------------------- bagg1: bucket-LDS layer-1 aggregate
// 1024 threads, ILP-4: per thread-chunk 4 consecutive staged entries, all
// payload loads issued before the LDS atomics. Native ds_add_u32 (exact).
__global__ __launch_bounds__(1024) void bagg1_kernel(
        const int* __restrict__ staged, const int* __restrict__ sbase,
        const unsigned* __restrict__ x8,
        float* __restrict__ aggr, int* __restrict__ degb, int N, int NB) {
    __shared__ unsigned xs[BW * 5];   // stride 5 (4 accum u32 + pad)
    __shared__ int ldeg[BW];
    int b = blockIdx.x, t = threadIdx.x;
    int base = b * BW;
    int s0 = sbase[b], s1 = sbase[b + 1];
    int len = s1 - s0;

    for (int i = t; i < BW * 5; i += 1024) xs[i] = 0u;
    if (t < BW) ldeg[t] = 0;
    __syncthreads();

    const unsigned M = 0x00FF00FFu;
    for (int i0 = t * 4; i0 < len; i0 += 4096) {
        int v0 = staged[s0 + i0];
        int v1 = (i0 + 1 < len) ? staged[s0 + i0 + 1] : -1;
        int v2 = (i0 + 2 < len) ? staged[s0 + i0 + 2] : -1;
        int v3 = (i0 + 3 < len) ? staged[s0 + i0 + 3] : -1;
        uint2 u0 = *(const uint2*)(x8 + (size_t)(v0 & 0x1FFFF) * 2);
        uint2 u1 = (v1 >= 0) ? *(const uint2*)(x8 + (size_t)(v1 & 0x1FFFF) * 2) : make_uint2(0, 0);
        uint2 u2 = (v2 >= 0) ? *(const uint2*)(x8 + (size_t)(v2 & 0x1FFFF) * 2) : make_uint2(0, 0);
        uint2 u3 = (v3 >= 0) ? *(const uint2*)(x8 + (size_t)(v3 & 0x1FFFF) * 2) : make_uint2(0, 0);
        {
            unsigned* xp = xs + (v0 >> 17) * 5;
            atomicAdd(xp + 0, u0.x & M); atomicAdd(xp + 1, (u0.x >> 8) & M);
            atomicAdd(xp + 2, u0.y & M); atomicAdd(xp + 3, (u0.y >> 8) & M);
            atomicAdd(&ldeg[v0 >> 17], 1);
        }
        if (v1 >= 0) {
            unsigned* xp = xs + (v1 >> 17) * 5;
            atomicAdd(xp + 0, u1.x & M); atomicAdd(xp + 1, (u1.x >> 8) & M);
            atomicAdd(xp + 2, u1.y & M); atomicAdd(xp + 3, (u1.y >> 8) & M);
            atomicAdd(&ldeg[v1 >> 17], 1);
        }
        if (v2 >= 0) {
            unsigned* xp = xs + (v2 >> 17) * 5;
            atomicAdd(xp + 0, u2.x & M); atomicAdd(xp + 1, (u2.x >> 8) & M);
            atomicAdd(xp + 2, u2.y & M); atomicAdd(xp + 3, (u2.y >> 8) & M);
            atomicAdd(&ldeg[v2 >> 17], 1);
        }
        if (v3 >= 0) {
            unsigned* xp = xs + (v3 >> 17) * 5;
            atomicAdd(xp + 0, u3.x & M); atomicAdd(xp + 1, (u3.x >> 8) & M);
            atomicAdd(xp + 2, u3.y & M); atomicAdd(xp + 3, (u3.y >> 8) & M);
            atomicAdd(&ldeg[v3 >> 17], 1);
        }
    }
    __syncthreads();

    if (t >= BW) return;
    int node = base + t;
    if (node >= N) return;
    int dg = ldeg[t];
    float bias = 128.0f * (float)dg;
    float inv = 1.0f / (X8SCALE * fmaxf((float)dg, 1.0f));
    unsigned Al0 = xs[t * 5 + 0], Ah0 = xs[t * 5 + 1];
    unsigned Al1 = xs[t * 5 + 2], Ah1 = xs[t * 5 + 3];
    float4 o0, o1;
    o0.x = ((float)(Al0 & 0xFFFF) - bias) * inv;
    o0.y = ((float)(Ah0 & 0xFFFF) - bias) * inv;
    o0.z = ((float)(Al0 >> 16) - bias) * inv;
    o0.w = ((float)(Ah0 >> 16) - bias) * inv;
    o1.x = ((float)(Al1 & 0xFFFF) - bias) * inv;
    o1.y = ((float)(Ah1 & 0xFFFF) - bias) * inv;
    o1.z = ((float)(Al1 >> 16) - bias) * inv;
    o1.w = ((float)(Ah1 >> 16) - bias) * inv;
    ((float4*)(aggr + (size_t)node * IN_CH))[0] = o0;
    ((float4*)(aggr + (size_t)node * IN_CH))[1] = o1;
    degb[node] = dg;
}

// ------------------------------------------------- dense1b: wave-uniform j-quarter split
__global__ __launch_bounds__(256) void dense1b_kernel(
        const float* __restrict__ x, const float* __restrict__ aggr,
        const float* __restrict__ b1, const float* __restrict__ b2,
        const unsigned* __restrict__ w1p, const unsigned* __restrict__ w2lp,
        const unsigned* __restrict__ w2rp,
        unsigned* __restrict__ p8, unsigned* __restrict__ selfh, int N) {
    int t = threadIdx.x;
    int w = t >> 6;                   // j-quarter 0..3 (wave-uniform)
    int lane = t & 63;
    int n = blockIdx.x * 64 + lane;
    if (n >= N) return;

    half2n uv[IN_CH];
    {
        float4 a0 = ((const float4*)(aggr + (size_t)n * IN_CH))[0];
        float4 a1 = ((const float4*)(aggr + (size_t)n * IN_CH))[1];
        float4 b0 = ((const float4*)(x + (size_t)n * IN_CH))[0];
        float4 b1v = ((const float4*)(x + (size_t)n * IN_CH))[1];
        uv[0] = mkh2(a0.x, b0.x); uv[1] = mkh2(a0.y, b0.y);
        uv[2] = mkh2(a0.z, b0.z); uv[3] = mkh2(a0.w, b0.w);
        uv[4] = mkh2(a1.x, b1v.x); uv[5] = mkh2(a1.y, b1v.y);
        uv[6] = mkh2(a1.z, b1v.z); uv[7] = mkh2(a1.w, b1v.w);
    }

    float pacc[8], sacc[8];
    const unsigned* w2lq = w2lp + w * 8;   // quarter base (wave-uniform)
    const unsigned* w2rq = w2rp + w * 8;
    #pragma unroll
    for (int j = 0; j < 8; j++) { pacc[j] = 0.0f; sacc[j] = b2[w * 8 + j]; }

    #pragma unroll 2
    for (int k2 = 0; k2 < HID / 2; k2++) {
        int k = 2 * k2;
        float h0 = b1[k], h1 = b1[k + 1];
        #pragma unroll
        for (int c = 0; c < IN_CH; c++) {
            h0 = fdot2w(uv[c], u2n(w1p[k * 8 + c]), h0);
            h1 = fdot2w(uv[c], u2n(w1p[(k + 1) * 8 + c]), h1);
        }
        h0 = fmaxf(h0, 0.0f);
        h1 = fmaxf(h1, 0.0f);
        half2n hh = mkh2(h0, h1);
        #pragma unroll
        for (int j = 0; j < 8; j++) {
            pacc[j] = fdot2w(hh, u2n(w2lq[k2 * EMB + j]), pacc[j]);
            sacc[j] = fdot2w(hh, u2n(w2rq[k2 * EMB + j]), sacc[j]);
        }
    }

    unsigned up[2];
    #pragma unroll
    for (int m = 0; m < 2; m++) {
        int q0 = min(127, max(-127, __float2int_rn(pacc[4 * m + 0] * P8SCALE)));
        int q1 = min(127, max(-127, __float2int_rn(pacc[4 * m + 1] * P8SCALE)));
        int q2 = min(127, max(-127, __float2int_rn(pacc[4 * m + 2] * P8SCALE)));
        int q3 = min(127, max(-127, __float2int_rn(pacc[4 * m + 3] * P8SCALE)));
        up[m] = ((unsigned)(q0 & 255) | ((unsigned)(q1 & 255) << 8)
              | ((unsigned)(q2 & 255) << 16) | ((unsigned)(q3 & 255) << 24)) ^ 0x80808080u;
    }
    ((uint2*)(p8 + (size_t)n * 8 + w * 2))[0] = make_uint2(up[0], up[1]);

    unsigned us[4];
    #pragma unroll
    for (int m = 0; m < 4; m++)
        us[m] = h22u(__floats2half2_rn(sacc[2 * m], sacc[2 * m + 1]));
    ((uint4*)(selfh + (size_t)n * 16 + w * 4))[0] = make_uint4(us[0], us[1], us[2], us[3]);
}

// ------------------------------------------------- bagg2: bucket-LDS layer-2 aggregate + head
// 1024 threads, ILP-4 staged entries; 16 native ds_add_u32 per edge (exact).
// Finalize thread-per-node: unbias + self + relu + head MLP + sigmoid.
__global__ __launch_bounds__(1024) void bagg2_kernel(
        const int* __restrict__ staged, const int* __restrict__ sbase,
        const unsigned* __restrict__ p8, const unsigned* __restrict__ selfh,
        const int* __restrict__ degb,
        const float* __restrict__ Wh1, const float* __restrict__ bh1,
        const float* __restrict__ Wh2, const float* __restrict__ bh2,
        float* __restrict__ out, int N, int NB) {
    __shared__ unsigned zs[BW * 17];  // 16 accum u32 per node + pad
    int b = blockIdx.x, t = threadIdx.x;
    int base = b * BW;
    int s0 = sbase[b], s1 = sbase[b + 1];
    int len = s1 - s0;

    for (int i = t; i < BW * 17; i += 1024) zs[i] = 0u;
    __syncthreads();

    const unsigned M = 0x00FF00FFu;
    for (int i0 = t * 4; i0 < len; i0 += 4096) {
        int v0 = staged[s0 + i0];
        int v1 = (i0 + 1 < len) ? staged[s0 + i0 + 1] : -1;
        int v2 = (i0 + 2 < len) ? staged[s0 + i0 + 2] : -1;
        int v3 = (i0 + 3 < len) ? staged[s0 + i0 + 3] : -1;
        const uint4* r0 = (const uint4*)(p8 + (size_t)(v0 & 0x1FFFF) * 8);
        uint4 a0 = r0[0], c0 = r0[1];
        uint4 a1, c1, a2, c2, a3, c3;
        if (v1 >= 0) { const uint4* r = (const uint4*)(p8 + (size_t)(v1 & 0x1FFFF) * 8); a1 = r[0]; c1 = r[1]; }
        if (v2 >= 0) { const uint4* r = (const uint4*)(p8 + (size_t)(v2 & 0x1FFFF) * 8); a2 = r[0]; c2 = r[1]; }
        if (v3 >= 0) { const uint4* r = (const uint4*)(p8 + (size_t)(v3 & 0x1FFFF) * 8); a3 = r[0]; c3 = r[1]; }
        {
            unsigned* zp = zs + (v0 >> 17) * 17;
            atomicAdd(zp + 0, a0.x & M);  atomicAdd(zp + 1, (a0.x >> 8) & M);
            atomicAdd(zp + 2, a0.y & M);  atomicAdd(zp + 3, (a0.y >> 8) & M);
            atomicAdd(zp + 4, a0.z & M);  atomicAdd(zp + 5, (a0.z >> 8) & M);
            atomicAdd(zp + 6, a0.w & M);  atomicAdd(zp + 7, (a0.w >> 8) & M);
            atomicAdd(zp + 8, c0.x & M);  atomicAdd(zp + 9, (c0.x >> 8) & M);
            atomicAdd(zp + 10, c0.y & M); atomicAdd(zp + 11, (c0.y >> 8) & M);
            atomicAdd(zp + 12, c0.z & M); atomicAdd(zp + 13, (c0.z >> 8) & M);
            atomicAdd(zp + 14, c0.w & M); atomicAdd(zp + 15, (c0.w >> 8) & M);
        }
        if (v1 >= 0) {
            unsigned* zp = zs + (v1 >> 17) * 17;
            atomicAdd(zp + 0, a1.x & M);  atomicAdd(zp + 1, (a1.x >> 8) & M);
            atomicAdd(zp + 2, a1.y & M);  atomicAdd(zp + 3, (a1.y >> 8) & M);
            atomicAdd(zp + 4, a1.z & M);  atomicAdd(zp + 5, (a1.z >> 8) & M);
            atomicAdd(zp + 6, a1.w & M);  atomicAdd(zp + 7, (a1.w >> 8) & M);
            atomicAdd(zp + 8, c1.x & M);  atomicAdd(zp + 9, (c1.x >> 8) & M);
            atomicAdd(zp + 10, c1.y & M); atomicAdd(zp + 11, (c1.y >> 8) & M);
            atomicAdd(zp + 12, c1.z & M); atomicAdd(zp + 13, (c1.z >> 8) & M);
            atomicAdd(zp + 14, c1.w & M); atomicAdd(zp + 15, (c1.w >> 8) & M);
        }
        if (v2 >= 0) {
            unsigned* zp = zs + (v2 >> 17) * 17;
            atomicAdd(zp + 0, a2.x & M);  atomicAdd(zp + 1, (a2.x >> 8) & M);
            atomicAdd(zp + 2, a2.y & M);  atomicAdd(zp + 3, (a2.y >> 8) & M);
            atomicAdd(zp + 4, a2.z & M);  atomicAdd(zp + 5, (a2.z >> 8) & M);
            atomicAdd(zp + 6, a2.w & M);  atomicAdd(zp + 7, (a2.w >> 8) & M);
            atomicAdd(zp + 8, c2.x & M);  atomicAdd(zp + 9, (c2.x >> 8) & M);
            atomicAdd(zp + 10, c2.y & M); atomicAdd(zp + 11, (c2.y >> 8) & M);
            atomicAdd(zp + 12, c2.z & M); atomicAdd(zp + 13, (c2.z >> 8) & M);
            atomicAdd(zp + 14, c2.w & M); atomicAdd(zp + 15, (c2.w >> 8) & M);
        }
        if (v3 >= 0) {
            unsigned* zp = zs + (v3 >> 17) * 17;
            atomicAdd(zp + 0, a3.x & M);  atomicAdd(zp + 1, (a3.x >> 8) & M);
            atomicAdd(zp + 2, a3.y & M);  atomicAdd(zp + 3, (a3.y >> 8) & M);
            atomicAdd(zp + 4, a3.z & M);  atomicAdd(zp + 5, (a3.z >> 8) & M);
            atomicAdd(zp + 6, a3.w & M);  atomicAdd(zp + 7, (a3.w >> 8) & M);
            atomicAdd(zp + 8, c3.x & M);  atomicAdd(zp + 9, (c3.x >> 8) & M);
            atomicAdd(zp + 10, c3.y & M); atomicAdd(zp + 11, (c3.y >> 8) & M);
            atomicAdd(zp + 12, c3.z & M); atomicAdd(zp + 13, (c3.z >> 8) & M);
            atomicAdd(zp + 14, c3.w & M); atomicAdd(zp + 15, (c3.w >> 8) & M);
        }
    }
    __syncthreads();

    if (t >= BW) return;
    int node = base + t;
    if (node >= N) return;
    int dg = degb[node];
    float bias = 128.0f * (float)dg;
    float sc = (1.0f / P8SCALE) / fmaxf((float)dg, 1.0f);

    float z[EMB];
    const uint2* sb = (const uint2*)(selfh + (size_t)node * 16);
    #pragma unroll
    for (int j = 0; j < 8; j++) {          // row uint j: channels 4j..4j+3
        unsigned lo = zs[t * 17 + 2 * j];
        unsigned hi = zs[t * 17 + 2 * j + 1];
        uint2 sh = sb[j];
        float2 c0 = __half22float2(u2h2(sh.x));
        float2 c1 = __half22float2(u2h2(sh.y));
        z[4 * j + 0] = fmaxf(((float)(lo & 0xFFFF) - bias) * sc + c0.x, 0.0f);
        z[4 * j + 1] = fmaxf(((float)(hi & 0xFFFF) - bias) * sc + c0.y, 0.0f);
        z[4 * j + 2] = fmaxf(((float)(lo >> 16) - bias) * sc + c1.x, 0.0f);
        z[4 * j + 3] = fmaxf(((float)(hi >> 16) - bias) * sc + c1.y, 0.0f);
    }

    float logit = bh2[0];
    #pragma unroll
    for (int i = 0; i < 16; i++) {
        float acc = bh1[i];
        #pragma unroll
        for (int k = 0; k < EMB; k++) acc += z[k] * Wh1[k * 16 + i];
        logit += fmaxf(acc, 0.0f) * Wh2[i];
    }
    out[node] = 1.0f / (1.0f + expf(-logit));
}

// ---------------------------------------------------------------- launch
extern "C" void kernel_launch(void* const* d_in, const int* in_sizes, int n_in,
                              void* d_out, int out_size, void* d_ws, size_t ws_size,
                              hipStream_t stream) {
    const float* x   = (const float*)d_in[0];
    const int*   ei  = (const int*)d_in[1];
    const float* W1l = (const float*)d_in[2];
    const float* b1  = (const float*)d_in[3];
    const float* W1r = (const float*)d_in[4];
    const float* W2l = (const float*)d_in[5];
    const float* b2  = (const float*)d_in[6];
    const float* W2r = (const float*)d_in[7];
    const float* Wh1 = (const float*)d_in[8];
    const float* bh1 = (const float*)d_in[9];
    const float* Wh2 = (const float*)d_in[10];
    const float* bh2 = (const float*)d_in[11];

    int N = in_sizes[0] / IN_CH;     // 100000
    int E = in_sizes[1] / 2;         // 3200000
    int NB = (N + BW - 1) / BW;      // 196 buckets
    int M  = NB * HBLK;              // blkoff cells
    int per = (((E + HBLK - 1) / HBLK) + 3) & ~3;   // per-block edge span, x4 aligned
    int PB = (N + 255) / 256;                       // prep blocks

    // workspace layout (all segments x4-int aligned):
    // [staged E][blkoff M][gcnt NB4][sbase NB4+4][degb N4]
    // [x8 2(N+2)][aggr 8N f32][selfh 16N][p8 8(N+1)][w1p 512][w2lp 1024][w2rp 1024]
    int N4 = (N + 3) & ~3;
    int NB4 = (NB + 3) & ~3;
    int* staged   = (int*)d_ws;
    int* blkoff   = staged + E;                     // E mult of 4
    int* gcnt     = blkoff + M;                     // M mult of 4
    int* sbase    = gcnt + NB4;
    int* degb     = sbase + NB4 + 4;
    unsigned* x8  = (unsigned*)(degb + N4);
    float* aggr   = (float*)(x8 + (size_t)(N + 2) * 2);
    unsigned* selfh = (unsigned*)(aggr + (size_t)N * IN_CH);
    unsigned* p8  = selfh + (size_t)N * 16;
    unsigned* w1p = p8 + (size_t)(N + 1) * 8 + 4;   // keep x4 alignment
    unsigned* w2lp = w1p + HID * IN_CH;
    unsigned* w2rp = w2lp + (HID / 2) * EMB;

    (void)hipMemsetAsync(gcnt, 0, sizeof(int) * NB4, stream);
    histprep_kernel<<<HBLK + PB, 256, 0, stream>>>(ei, gcnt, blkoff, E, NB, per,
                                                   x, x8, W1l, W1r, W2l, W2r,
                                                   w1p, w2lp, w2rp, N);
    bscan_kernel  <<<1, 256, 0, stream>>>(gcnt, sbase, E, NB);
    scat_kernel   <<<HBLK, 512, 0, stream>>>(ei, sbase, blkoff, staged, E, NB, per);
    bagg1_kernel  <<<NB, 1024, 0, stream>>>(staged, sbase, x8, aggr, degb, N, NB);
    dense1b_kernel<<<(N + 63) / 64, 256, 0, stream>>>(x, aggr, b1, b2,
                                                      w1p, w2lp, w2rp, p8, selfh, N);
    bagg2_kernel  <<<NB, 1024, 0, stream>>>(staged, sbase, p8, selfh, degb,
                                            Wh1, bh1, Wh2, bh2, (float*)d_out, N, NB);
}